// Round 6
// baseline (1050.309 us; speedup 1.0000x reference)
//
#include <hip/hip_runtime.h>

typedef unsigned short u16;
typedef __attribute__((ext_vector_type(8))) short s16x8;
typedef __attribute__((ext_vector_type(4))) float f32x4;
typedef __attribute__((ext_vector_type(4))) unsigned short u16x4;

#define NB 8
#define SS 1024
#define HH 768
#define NHD 12
#define DHD 64
#define FFD 3072
#define RR 64
#define NEC 512
#define EIC 4096

__device__ __forceinline__ float b2f(u16 u){ return __uint_as_float(((unsigned)u)<<16); }
__device__ __forceinline__ u16 f2b(float f){
  unsigned x = __float_as_uint(f);
  return (u16)((x + 0x7fffu + ((x>>16)&1u)) >> 16);   // RNE
}
__device__ __forceinline__ float gelu_f(float x){
  return 0.5f*x*(1.0f + tanhf(0.79788456080286535588f*(x + 0.044715f*x*x*x)));
}

// ---------------------------------------------------------------- transpose
// dst[c][r] = bf16(src[r][c]); src fp32, dst bf16. R,C mult of 64.
// grid (R/64, C/64), block 256.
__global__ __launch_bounds__(256)
void wtrans(const float* __restrict__ src, u16* __restrict__ dst, int R, int C)
{
  __shared__ u16 tile[64][68];
  const int r0 = blockIdx.x*64, c0 = blockIdx.y*64;
  const int t = threadIdx.x;
  const int tr = t >> 4, tc = (t & 15) * 4;
  for (int i = 0; i < 4; i++) {
    int r = tr + i*16;
    float4 v4 = *(const float4*)&src[(size_t)(r0+r)*C + c0 + tc];
    u16x4 h; h.x = f2b(v4.x); h.y = f2b(v4.y); h.z = f2b(v4.z); h.w = f2b(v4.w);
    *(u16x4*)&tile[r][tc] = h;
  }
  __syncthreads();
  for (int i = 0; i < 4; i++) {
    int rr = tr + i*16;                 // dst row within tile (= src col)
    u16x4 v;
    v.x = tile[tc+0][rr]; v.y = tile[tc+1][rr];
    v.z = tile[tc+2][rr]; v.w = tile[tc+3][rr];
    *(u16x4*)&dst[(size_t)(c0+rr)*R + r0 + tc] = v;
  }
}

// V (bf16) [B,S,NH,DH] -> Vt (bf16) [B*NH][DH][S]. grid (S/64, B*NH), block 256.
__global__ __launch_bounds__(256)
void vtrans(const u16* __restrict__ v, u16* __restrict__ vt)
{
  __shared__ u16 tile[64][68];
  const int st = blockIdx.x, bh = blockIdx.y;
  const int b = bh / NHD, h = bh - b*NHD;
  const u16* src = v + ((size_t)(b*SS + st*64)*NHD + h)*DHD;
  u16* dst = vt + (size_t)bh*DHD*SS + st*64;
  const int t = threadIdx.x;
  const int tr = t >> 4, tc = (t & 15) * 4;
  for (int i = 0; i < 4; i++) {
    int r = tr + i*16;                  // s-local row
    *(u16x4*)&tile[r][tc] = *(const u16x4*)&src[(size_t)r*HH + tc];
  }
  __syncthreads();
  for (int i = 0; i < 4; i++) {
    int rr = tr + i*16;                 // d row
    u16x4 vv;
    vv.x = tile[tc+0][rr]; vv.y = tile[tc+1][rr];
    vv.z = tile[tc+2][rr]; vv.w = tile[tc+3][rr];
    *(u16x4*)&dst[(size_t)rr*SS + tc] = vv;
  }
}

// ---------------------------------------------------------------- GEMM
// C[M,N] = act(A[M,K] @ Bt[N,K]^T + bias).  BK=64, 4 waves (2x2).
// AIN: 0 = A fp32 (convert to bf16 during LDS staging), 1 = A bf16.
// OUT: 0 = C fp32, 1 = C bf16.  Bt always bf16 (pre-packed), bias fp32.
// mfma_f32_16x16x32_bf16 layouts per learn_hip m89/m91/m92.
template<int BM, int BN, int ACT, int AIN, int OUT>
__global__ __launch_bounds__(256)
void gemm_bt(const void* __restrict__ Av, const u16* __restrict__ Bt,
             const float* __restrict__ bias, void* __restrict__ Cv,
             int M, int N, int K)
{
  constexpr int MF = BM/32;   // frags per wave in M (wave tile BM/2)
  constexpr int NF = BN/32;
  __shared__ __align__(16) u16 lsA[BM][72];
  __shared__ __align__(16) u16 lsB[BN][72];
  const int m0 = blockIdx.y*BM, n0 = blockIdx.x*BN;
  const int t = threadIdx.x, lane = t & 63, w = t >> 6;
  const int wm = w >> 1, wn = w & 1;
  const int l15 = lane & 15, lg = lane >> 4;

  f32x4 acc[MF][NF];
  #pragma unroll
  for (int i = 0; i < MF; i++)
    #pragma unroll
    for (int j = 0; j < NF; j++) acc[i][j] = (f32x4){0.f,0.f,0.f,0.f};

  for (int k0 = 0; k0 < K; k0 += 64) {
    __syncthreads();
    if constexpr (AIN == 0) {
      const float* A = (const float*)Av;
      for (int c = t; c < BM*16; c += 256) {
        int r = c >> 4, cc = (c & 15) << 2;
        float4 v4 = *(const float4*)&A[(size_t)(m0+r)*K + k0 + cc];
        u16x4 h; h.x = f2b(v4.x); h.y = f2b(v4.y); h.z = f2b(v4.z); h.w = f2b(v4.w);
        *(u16x4*)&lsA[r][cc] = h;
      }
    } else {
      const u16* A = (const u16*)Av;
      for (int c = t; c < BM*8; c += 256) {
        int r = c >> 3, cc = (c & 7) << 3;
        *(s16x8*)&lsA[r][cc] = *(const s16x8*)&A[(size_t)(m0+r)*K + k0 + cc];
      }
    }
    for (int c = t; c < BN*8; c += 256) {
      int r = c >> 3, cc = (c & 7) << 3;
      *(s16x8*)&lsB[r][cc] = *(const s16x8*)&Bt[(size_t)(n0+r)*K + k0 + cc];
    }
    __syncthreads();
    #pragma unroll
    for (int kk = 0; kk < 64; kk += 32) {
      const int ko = kk + (lg << 3);
      s16x8 af[MF], bfr[NF];
      #pragma unroll
      for (int i = 0; i < MF; i++)
        af[i] = *(const s16x8*)&lsA[wm*(BM/2) + i*16 + l15][ko];
      #pragma unroll
      for (int j = 0; j < NF; j++)
        bfr[j] = *(const s16x8*)&lsB[wn*(BN/2) + j*16 + l15][ko];
      #pragma unroll
      for (int i = 0; i < MF; i++)
        #pragma unroll
        for (int j = 0; j < NF; j++)
          acc[i][j] = __builtin_amdgcn_mfma_f32_16x16x32_bf16(af[i], bfr[j], acc[i][j], 0, 0, 0);
    }
  }
  #pragma unroll
  for (int j = 0; j < NF; j++) {
    const int col = n0 + wn*(BN/2) + j*16 + l15;
    const float bv = bias[col];
    #pragma unroll
    for (int i = 0; i < MF; i++) {
      #pragma unroll
      for (int r = 0; r < 4; r++) {
        const int row = m0 + wm*(BM/2) + i*16 + (lg << 2) + r;
        float v = acc[i][j][r] + bv;
        if (ACT == 1) v = gelu_f(v);
        if constexpr (OUT == 0) ((float*)Cv)[(size_t)row*N + col] = v;
        else                    ((u16*)Cv)[(size_t)row*N + col] = f2b(v);
      }
    }
  }
}

// ---------------------------------------------------------------- attention
// q,k bf16 [B*S][H]; vt bf16 [B*NH][DH][S]; ctx bf16 [B*S][H].
// grid (S/64, B*NH), block 256 (4 waves; wave w owns 16 q-rows).
__global__ __launch_bounds__(256)
void attn_fwd(const u16* __restrict__ q, const u16* __restrict__ k,
              const u16* __restrict__ vt, u16* __restrict__ ctx)
{
  const int qt = blockIdx.x, bh = blockIdx.y;
  const int b = bh / NHD, h = bh - b*NHD;
  __shared__ __align__(16) u16 lsK[64][72];
  __shared__ __align__(16) u16 lsV[64][72];
  __shared__ __align__(16) u16 lsP[4][16][72];
  const int t = threadIdx.x, lane = t & 63, w = t >> 6;
  const int l15 = lane & 15, lg = lane >> 4;

  const int qrow = qt*64 + w*16 + l15;
  const size_t qoff = ((size_t)(b*SS + qrow)*NHD + h)*DHD;
  const s16x8 qf0 = *(const s16x8*)&q[qoff + (lg << 3)];
  const s16x8 qf1 = *(const s16x8*)&q[qoff + 32 + (lg << 3)];

  float m_run[4], l_run[4];
  f32x4 oacc[4];
  #pragma unroll
  for (int r = 0; r < 4; r++) { m_run[r] = -1e30f; l_run[r] = 0.f; }
  #pragma unroll
  for (int j = 0; j < 4; j++) oacc[j] = (f32x4){0.f,0.f,0.f,0.f};

  const u16* kbase = k + ((size_t)(b*SS)*NHD + h)*DHD;
  const u16* vbase = vt + (size_t)bh*DHD*SS;

  for (int kt = 0; kt < SS/64; kt++) {
    __syncthreads();
    for (int c = t; c < 512; c += 256) {
      int r = c >> 3, cc = (c & 7) << 3;
      *(s16x8*)&lsK[r][cc] = *(const s16x8*)&kbase[(size_t)(kt*64 + r)*HH + cc];
    }
    for (int c = t; c < 512; c += 256) {
      int r = c >> 3, cc = (c & 7) << 3;
      *(s16x8*)&lsV[r][cc] = *(const s16x8*)&vbase[(size_t)r*SS + kt*64 + cc];
    }
    __syncthreads();

    f32x4 sc[4];
    #pragma unroll
    for (int nf = 0; nf < 4; nf++) sc[nf] = (f32x4){0.f,0.f,0.f,0.f};
    #pragma unroll
    for (int kk = 0; kk < 2; kk++) {
      const int ko = kk*32 + (lg << 3);
      const s16x8 a = kk ? qf1 : qf0;
      #pragma unroll
      for (int nf = 0; nf < 4; nf++) {
        s16x8 kf = *(const s16x8*)&lsK[nf*16 + l15][ko];
        sc[nf] = __builtin_amdgcn_mfma_f32_16x16x32_bf16(a, kf, sc[nf], 0, 0, 0);
      }
    }
    // online softmax (rows r: row=(lg<<2)+r, cols nf*16+l15; scale 1/8)
    float alpha[4], pv[4][4];
    #pragma unroll
    for (int r = 0; r < 4; r++) {
      float mx = fmaxf(fmaxf(sc[0][r], sc[1][r]), fmaxf(sc[2][r], sc[3][r])) * 0.125f;
      #pragma unroll
      for (int o = 1; o < 16; o <<= 1) mx = fmaxf(mx, __shfl_xor(mx, o, 64));
      const float nm = fmaxf(m_run[r], mx);
      alpha[r] = __expf(m_run[r] - nm);
      float sum = 0.f;
      #pragma unroll
      for (int nf = 0; nf < 4; nf++) {
        float p = __expf(sc[nf][r]*0.125f - nm);
        pv[nf][r] = p; sum += p;
      }
      #pragma unroll
      for (int o = 1; o < 16; o <<= 1) sum += __shfl_xor(sum, o, 64);
      l_run[r] = l_run[r]*alpha[r] + sum;
      m_run[r] = nm;
    }
    #pragma unroll
    for (int j = 0; j < 4; j++) {
      f32x4 o = oacc[j];
      o[0] *= alpha[0]; o[1] *= alpha[1]; o[2] *= alpha[2]; o[3] *= alpha[3];
      oacc[j] = o;
    }
    #pragma unroll
    for (int nf = 0; nf < 4; nf++)
      #pragma unroll
      for (int r = 0; r < 4; r++)
        lsP[w][(lg << 2) + r][nf*16 + l15] = f2b(pv[nf][r]);
    __syncthreads();
    #pragma unroll
    for (int ks = 0; ks < 2; ks++) {
      const int ko = ks*32 + (lg << 3);
      const s16x8 pf = *(const s16x8*)&lsP[w][l15][ko];
      #pragma unroll
      for (int j = 0; j < 4; j++) {
        s16x8 vf = *(const s16x8*)&lsV[j*16 + l15][ko];
        oacc[j] = __builtin_amdgcn_mfma_f32_16x16x32_bf16(pf, vf, oacc[j], 0, 0, 0);
      }
    }
  }
  #pragma unroll
  for (int j = 0; j < 4; j++)
    #pragma unroll
    for (int r = 0; r < 4; r++) {
      const int row = qt*64 + w*16 + (lg << 2) + r;
      ctx[((size_t)(b*SS + row))*HH + h*DHD + j*16 + l15] = f2b(oacc[j][r] / l_run[r]);
    }
}

// ---------------------------------------------------------------- adapter
// d fp32 [B*S][R]; 4 edges(block), 64 lanes = R features.
__global__ __launch_bounds__(256)
void adp_gather(const float* __restrict__ d, const int* __restrict__ nidx,
                const int* __restrict__ eidx, float* __restrict__ esum,
                float* __restrict__ ecnt)
{
  const int gi = blockIdx.x*4 + (threadIdx.x >> 6);
  const int lane = threadIdx.x & 63;
  const int b = gi >> 12, i = gi & (EIC - 1);
  const int n = nidx[(size_t)b*EIC + i];
  const int e = eidx[(size_t)b*EIC + i];
  const float val = d[((size_t)b*SS + n)*RR + lane];
  atomicAdd(&esum[((size_t)b*NEC + e)*RR + lane], val);
  if (lane == 0) atomicAdd(&ecnt[(size_t)b*NEC + e], 1.0f);
}

__global__ __launch_bounds__(256)
void adp_edge(const float* __restrict__ esum, const float* __restrict__ ecnt,
              const int* __restrict__ types, const float* __restrict__ temb,
              float* __restrict__ e_out)
{
  const int ge = blockIdx.x*4 + (threadIdx.x >> 6);
  const int lane = threadIdx.x & 63;
  const int b = ge >> 9, e = ge & (NEC - 1);
  const float cnt = fmaxf(ecnt[(size_t)b*NEC + e], 1.0f);
  const int ty = types[(size_t)b*NEC + e];
  e_out[((size_t)b*NEC + e)*RR + lane] =
      esum[((size_t)b*NEC + e)*RR + lane]/cnt + temb[(size_t)ty*RR + lane];
}

__global__ __launch_bounds__(256)
void adp_scatter(const float* __restrict__ e_out, const int* __restrict__ nidx,
                 const int* __restrict__ eidx, float* __restrict__ nsum,
                 float* __restrict__ ncnt)
{
  const int gi = blockIdx.x*4 + (threadIdx.x >> 6);
  const int lane = threadIdx.x & 63;
  const int b = gi >> 12, i = gi & (EIC - 1);
  const int n = nidx[(size_t)b*EIC + i];
  const int e = eidx[(size_t)b*EIC + i];
  atomicAdd(&nsum[((size_t)b*SS + n)*RR + lane], e_out[((size_t)b*NEC + e)*RR + lane]);
  if (lane == 0) atomicAdd(&ncnt[(size_t)b*SS + n], 1.0f);
}

__global__ __launch_bounds__(256)
void adp_node(const float* __restrict__ nsum, const float* __restrict__ ncnt,
              float* __restrict__ u)
{
  const int gn = blockIdx.x*4 + (threadIdx.x >> 6);
  const int lane = threadIdx.x & 63;
  const float cnt = fmaxf(ncnt[gn], 1.0f);
  u[(size_t)gn*RR + lane] = nsum[(size_t)gn*RR + lane]/cnt;
}

// ---------------------------------------------------------------- layernorm
// out = LN(a + b + c)*g + beta.  All fp32. grid = rows (8192), block 256.
__global__ __launch_bounds__(256)
void ln3(const float* __restrict__ a, const float* __restrict__ bb,
         const float* __restrict__ c, const float* __restrict__ g,
         const float* __restrict__ be, float* __restrict__ out)
{
  const int row = blockIdx.x, t = threadIdx.x;
  const size_t base = (size_t)row*HH;
  float v[3]; float s = 0.f, s2 = 0.f;
  #pragma unroll
  for (int i = 0; i < 3; i++) {
    int col = t + i*256;
    float x = a[base+col] + bb[base+col] + c[base+col];
    v[i] = x; s += x; s2 += x*x;
  }
  #pragma unroll
  for (int o = 1; o < 64; o <<= 1) { s += __shfl_xor(s, o, 64); s2 += __shfl_xor(s2, o, 64); }
  __shared__ float red[2][4];
  if ((t & 63) == 0) { red[0][t>>6] = s; red[1][t>>6] = s2; }
  __syncthreads();
  const float S  = red[0][0]+red[0][1]+red[0][2]+red[0][3];
  const float S2 = red[1][0]+red[1][1]+red[1][2]+red[1][3];
  const float mean = S*(1.0f/HH);
  const float var  = S2*(1.0f/HH) - mean*mean;
  const float inv  = rsqrtf(var + 1e-5f);
  #pragma unroll
  for (int i = 0; i < 3; i++) {
    int col = t + i*256;
    out[base+col] = (v[i]-mean)*inv*g[col] + be[col];
  }
}

// ---------------------------------------------------------------- host
extern "C" void kernel_launch(void* const* d_in, const int* in_sizes, int n_in,
                              void* d_out, int out_size, void* d_ws, size_t ws_size,
                              hipStream_t stream)
{
  (void)in_sizes; (void)n_in; (void)out_size; (void)ws_size;
  const float* x        = (const float*)d_in[0];
  const int* node_idx   = (const int*)d_in[1];
  const int* edge_idx   = (const int*)d_in[2];
  const int* edge_types = (const int*)d_in[3];
  const float* Wq = (const float*)d_in[4];  const float* bq = (const float*)d_in[5];
  const float* Wk = (const float*)d_in[6];  const float* bk = (const float*)d_in[7];
  const float* Wv = (const float*)d_in[8];  const float* bv = (const float*)d_in[9];
  const float* Wo = (const float*)d_in[10]; const float* bo = (const float*)d_in[11];
  const float* ln1_g = (const float*)d_in[12]; const float* ln1_b = (const float*)d_in[13];
  const float* a1_dw = (const float*)d_in[14]; const float* a1_db = (const float*)d_in[15];
  const float* a1_uw = (const float*)d_in[16]; const float* a1_ub = (const float*)d_in[17];
  const float* a1_temb = (const float*)d_in[18];
  const float* Wi  = (const float*)d_in[19]; const float* bi  = (const float*)d_in[20];
  const float* Wd2 = (const float*)d_in[21]; const float* bd2 = (const float*)d_in[22];
  const float* ln2_g = (const float*)d_in[23]; const float* ln2_b = (const float*)d_in[24];
  const float* a2_dw = (const float*)d_in[25]; const float* a2_db = (const float*)d_in[26];
  const float* a2_uw = (const float*)d_in[27]; const float* a2_ub = (const float*)d_in[28];
  const float* a2_temb = (const float*)d_in[29];

  char* ws = (char*)d_ws;
  size_t off = 0;
  auto take = [&](size_t bytes) -> size_t {
    size_t o = off; off += (bytes + 255) & ~(size_t)255; return o;
  };
  const size_t actB2 = (size_t)8192*768*2;   // bf16 [B*S, H]
  const size_t actB4 = (size_t)8192*768*4;   // fp32 [B*S, H]
  const size_t oWqT  = take(768ull*768*2);
  const size_t oWkT  = take(768ull*768*2);
  const size_t oWvT  = take(768ull*768*2);
  const size_t oWoT  = take(768ull*768*2);
  const size_t oWiT  = take(768ull*3072*2);
  const size_t oWd2T = take(768ull*3072*2);
  const size_t oA1dwT = take(768ull*64*2);
  const size_t oA1uwT = take(768ull*64*2);
  const size_t oA2dwT = take(768ull*64*2);
  const size_t oA2uwT = take(768ull*64*2);
  const size_t oQ   = take(actB2);   // bf16; later reused as inter (bf16, 4x)
  const size_t oK   = take(actB2);
  const size_t oV   = take(actB2);
  const size_t oVt  = take(actB2);   // [96][64][1024]
  const size_t oCtx = take(actB2);   // bf16; later reused (with oAD head) as ffb
  const size_t oAD  = take(actB4);   // attn_dense fp32
  const size_t oAd  = take(actB4);   // adapter output fp32 (shared 1/2)
  const size_t oAO  = take(actB4);   // attn_out fp32
  const size_t oDb  = take((size_t)8192*64*4);
  const size_t oUb  = take((size_t)8192*64*4);
  const size_t oEsum = take((size_t)8*512*64*4);
  const size_t oEcnt = take((size_t)8*512*4);
  const size_t oNsum = take((size_t)8*1024*64*4);
  const size_t oNcnt = take((size_t)8*1024*4);
  const size_t oEbuf = take((size_t)8*512*64*4);
  const size_t oInter = oQ;    // bf16 [8192][3072] = 4 x actB2 (q,k,v,vt dead)
  const size_t oFF    = oCtx;  // fp32 [8192][768] = 25.2MB over ctx+AD-head (both dead)
  const size_t zeroBytes = oEbuf - oEsum;   // esum..ncnt contiguous

  u16* WqT = (u16*)(ws+oWqT);   u16* WkT = (u16*)(ws+oWkT);
  u16* WvT = (u16*)(ws+oWvT);   u16* WoT = (u16*)(ws+oWoT);
  u16* WiT = (u16*)(ws+oWiT);   u16* Wd2T = (u16*)(ws+oWd2T);
  u16* A1dwT = (u16*)(ws+oA1dwT); u16* A1uwT = (u16*)(ws+oA1uwT);
  u16* A2dwT = (u16*)(ws+oA2dwT); u16* A2uwT = (u16*)(ws+oA2uwT);
  u16* qb = (u16*)(ws+oQ);  u16* kb = (u16*)(ws+oK);  u16* vb = (u16*)(ws+oV);
  u16* vtb = (u16*)(ws+oVt); u16* ctx = (u16*)(ws+oCtx);
  float* attn_dense = (float*)(ws+oAD); float* adb = (float*)(ws+oAd);
  float* attn_out = (float*)(ws+oAO);
  float* dbuf = (float*)(ws+oDb); float* ubuf = (float*)(ws+oUb);
  float* esum = (float*)(ws+oEsum); float* ecnt = (float*)(ws+oEcnt);
  float* nsum = (float*)(ws+oNsum); float* ncnt = (float*)(ws+oNcnt);
  float* ebuf = (float*)(ws+oEbuf);
  u16* inter = (u16*)(ws+oInter); float* ffb = (float*)(ws+oFF);

  const dim3 blk(256);
  // weight packs: fp32 -> bf16 Bt layout
  wtrans<<<dim3(12,12), blk, 0, stream>>>(Wq,  WqT,  768, 768);
  wtrans<<<dim3(12,12), blk, 0, stream>>>(Wk,  WkT,  768, 768);
  wtrans<<<dim3(12,12), blk, 0, stream>>>(Wv,  WvT,  768, 768);
  wtrans<<<dim3(12,12), blk, 0, stream>>>(Wo,  WoT,  768, 768);
  wtrans<<<dim3(12,48), blk, 0, stream>>>(Wi,  WiT,  768, 3072);
  wtrans<<<dim3(48,12), blk, 0, stream>>>(Wd2, Wd2T, 3072, 768);
  wtrans<<<dim3(12,1),  blk, 0, stream>>>(a1_dw, A1dwT, 768, 64);
  wtrans<<<dim3(1,12),  blk, 0, stream>>>(a1_uw, A1uwT, 64, 768);
  wtrans<<<dim3(12,1),  blk, 0, stream>>>(a2_dw, A2dwT, 768, 64);
  wtrans<<<dim3(1,12),  blk, 0, stream>>>(a2_uw, A2uwT, 64, 768);
  // QKV: A fp32 -> bf16 out
  gemm_bt<128,128,0,0,1><<<dim3(6,64), blk, 0, stream>>>(x, WqT, bq, qb, 8192, 768, 768);
  gemm_bt<128,128,0,0,1><<<dim3(6,64), blk, 0, stream>>>(x, WkT, bk, kb, 8192, 768, 768);
  gemm_bt<128,128,0,0,1><<<dim3(6,64), blk, 0, stream>>>(x, WvT, bv, vb, 8192, 768, 768);
  vtrans<<<dim3(16,96), blk, 0, stream>>>(vb, vtb);
  attn_fwd<<<dim3(16,96), blk, 0, stream>>>(qb, kb, vtb, ctx);
  gemm_bt<128,128,0,1,0><<<dim3(6,64), blk, 0, stream>>>(ctx, WoT, bo, attn_dense, 8192, 768, 768);
  // adapter 1 (input attn_dense fp32)
  gemm_bt<128,64,1,0,0><<<dim3(1,64), blk, 0, stream>>>(attn_dense, A1dwT, a1_db, dbuf, 8192, 64, 768);
  hipMemsetAsync(ws + oEsum, 0, zeroBytes, stream);
  adp_gather<<<8192, blk, 0, stream>>>(dbuf, node_idx, edge_idx, esum, ecnt);
  adp_edge<<<1024, blk, 0, stream>>>(esum, ecnt, edge_types, a1_temb, ebuf);
  adp_scatter<<<8192, blk, 0, stream>>>(ebuf, node_idx, edge_idx, nsum, ncnt);
  adp_node<<<2048, blk, 0, stream>>>(nsum, ncnt, ubuf);
  gemm_bt<128,128,0,0,0><<<dim3(6,64), blk, 0, stream>>>(ubuf, A1uwT, a1_ub, adb, 8192, 768, 64);
  ln3<<<8192, blk, 0, stream>>>(attn_dense, adb, x, ln1_g, ln1_b, attn_out);
  // FFN
  gemm_bt<128,128,1,0,1><<<dim3(24,64), blk, 0, stream>>>(attn_out, WiT, bi, inter, 8192, 3072, 768);
  gemm_bt<128,128,0,1,0><<<dim3(6,64), blk, 0, stream>>>(inter, Wd2T, bd2, ffb, 8192, 768, 3072);
  // adapter 2 (input ff fp32)
  gemm_bt<128,64,1,0,0><<<dim3(1,64), blk, 0, stream>>>(ffb, A2dwT, a2_db, dbuf, 8192, 64, 768);
  hipMemsetAsync(ws + oEsum, 0, zeroBytes, stream);
  adp_gather<<<8192, blk, 0, stream>>>(dbuf, node_idx, edge_idx, esum, ecnt);
  adp_edge<<<1024, blk, 0, stream>>>(esum, ecnt, edge_types, a2_temb, ebuf);
  adp_scatter<<<8192, blk, 0, stream>>>(ebuf, node_idx, edge_idx, nsum, ncnt);
  adp_node<<<2048, blk, 0, stream>>>(nsum, ncnt, ubuf);
  gemm_bt<128,128,0,0,0><<<dim3(6,64), blk, 0, stream>>>(ubuf, A2uwT, a2_ub, adb, 8192, 768, 64);
  // final LN -> d_out (fp32)
  ln3<<<8192, blk, 0, stream>>>(ffb, adb, attn_out, ln2_g, ln2_b, (float*)d_out);
}

// Round 7
// 809.829 us; speedup vs baseline: 1.2970x; 1.2970x over previous
//
#include <hip/hip_runtime.h>

typedef unsigned short u16;
typedef __attribute__((ext_vector_type(8))) short s16x8;
typedef __attribute__((ext_vector_type(4))) float f32x4;
typedef __attribute__((ext_vector_type(4))) unsigned short u16x4;

#define NB 8
#define SS 1024
#define HH 768
#define NHD 12
#define DHD 64
#define FFD 3072
#define RR 64
#define NEC 512
#define EIC 4096

__device__ __forceinline__ float b2f(u16 u){ return __uint_as_float(((unsigned)u)<<16); }
__device__ __forceinline__ u16 f2b(float f){
  unsigned x = __float_as_uint(f);
  return (u16)((x + 0x7fffu + ((x>>16)&1u)) >> 16);   // RNE
}
__device__ __forceinline__ float gelu_f(float x){
  return 0.5f*x*(1.0f + tanhf(0.79788456080286535588f*(x + 0.044715f*x*x*x)));
}
// bijective XCD-chunked swizzle (m204): blocks with consecutive flat ids
// (which share A-panels / KV-heads) land on the SAME XCD's L2.
__device__ __forceinline__ void xcd_swz(int gx, int gy, int& bx, int& by){
  const int nwg = gx*gy;
  const int flat = by*gx + bx;
  const int qch = nwg >> 3, rch = nwg & 7;
  const int xcd = flat & 7, idx = flat >> 3;
  const int swz = (xcd < rch ? xcd*(qch+1) : rch*(qch+1) + (xcd-rch)*qch) + idx;
  bx = swz % gx; by = swz / gx;
}

// ---------------------------------------------------------------- fp32->bf16
__global__ __launch_bounds__(256)
void cvt16(const float* __restrict__ src, u16* __restrict__ dst)
{
  const size_t i = ((size_t)blockIdx.x*256 + threadIdx.x)*8;
  float4 a = *(const float4*)&src[i];
  float4 b = *(const float4*)&src[i+4];
  u16x4 h1; h1.x=f2b(a.x); h1.y=f2b(a.y); h1.z=f2b(a.z); h1.w=f2b(a.w);
  u16x4 h2; h2.x=f2b(b.x); h2.y=f2b(b.y); h2.z=f2b(b.z); h2.w=f2b(b.w);
  *(u16x4*)&dst[i] = h1; *(u16x4*)&dst[i+4] = h2;
}

// ---------------------------------------------------------------- transpose
// dst[c][r] = bf16(src[r][c]); src fp32. grid (R/64, C/64), block 256.
__global__ __launch_bounds__(256)
void wtrans(const float* __restrict__ src, u16* __restrict__ dst, int R, int C)
{
  __shared__ u16 tile[64][68];
  const int r0 = blockIdx.x*64, c0 = blockIdx.y*64;
  const int t = threadIdx.x;
  const int tr = t >> 4, tc = (t & 15) * 4;
  for (int i = 0; i < 4; i++) {
    int r = tr + i*16;
    float4 v4 = *(const float4*)&src[(size_t)(r0+r)*C + c0 + tc];
    u16x4 h; h.x = f2b(v4.x); h.y = f2b(v4.y); h.z = f2b(v4.z); h.w = f2b(v4.w);
    *(u16x4*)&tile[r][tc] = h;
  }
  __syncthreads();
  for (int i = 0; i < 4; i++) {
    int rr = tr + i*16;
    u16x4 v;
    v.x = tile[tc+0][rr]; v.y = tile[tc+1][rr];
    v.z = tile[tc+2][rr]; v.w = tile[tc+3][rr];
    *(u16x4*)&dst[(size_t)(c0+rr)*R + r0 + tc] = v;
  }
}

// V (bf16, row stride vs) -> Vt [B*NH][DH][S]. grid (S/64, B*NH), block 256.
__global__ __launch_bounds__(256)
void vtrans(const u16* __restrict__ v, u16* __restrict__ vt, int vs)
{
  __shared__ u16 tile[64][68];
  const int st = blockIdx.x, bh = blockIdx.y;
  const int b = bh / NHD, h = bh - b*NHD;
  const u16* src = v + (size_t)(b*SS + st*64)*vs + h*DHD;
  u16* dst = vt + (size_t)bh*DHD*SS + st*64;
  const int t = threadIdx.x;
  const int tr = t >> 4, tc = (t & 15) * 4;
  for (int i = 0; i < 4; i++) {
    int r = tr + i*16;
    *(u16x4*)&tile[r][tc] = *(const u16x4*)&src[(size_t)r*vs + tc];
  }
  __syncthreads();
  for (int i = 0; i < 4; i++) {
    int rr = tr + i*16;
    u16x4 vv;
    vv.x = tile[tc+0][rr]; vv.y = tile[tc+1][rr];
    vv.z = tile[tc+2][rr]; vv.w = tile[tc+3][rr];
    *(u16x4*)&dst[(size_t)rr*SS + tc] = vv;
  }
}

// ---------------------------------------------------------------- GEMM
// C = act(A[M,K](bf16) @ Bt[N,K]^T + bias). BK=64, 4 waves (2x2).
// OUT: 0 = fp32 only, 1 = bf16 only, 2 = both. grid (N/BN, M/BM), XCD-swizzled.
template<int BM, int BN, int ACT, int OUT>
__global__ __launch_bounds__(256)
void gemm_bt(const u16* __restrict__ A, const u16* __restrict__ Bt,
             const float* __restrict__ bias, float* __restrict__ C32,
             u16* __restrict__ C16, int M, int N, int K)
{
  constexpr int MF = BM/32;
  constexpr int NF = BN/32;
  __shared__ __align__(16) u16 lsA[BM][72];
  __shared__ __align__(16) u16 lsB[BN][72];
  int bx = blockIdx.x, by = blockIdx.y;
  xcd_swz(gridDim.x, gridDim.y, bx, by);
  const int m0 = by*BM, n0 = bx*BN;
  const int t = threadIdx.x, lane = t & 63, w = t >> 6;
  const int wm = w >> 1, wn = w & 1;
  const int l15 = lane & 15, lg = lane >> 4;

  f32x4 acc[MF][NF];
  #pragma unroll
  for (int i = 0; i < MF; i++)
    #pragma unroll
    for (int j = 0; j < NF; j++) acc[i][j] = (f32x4){0.f,0.f,0.f,0.f};

  for (int k0 = 0; k0 < K; k0 += 64) {
    __syncthreads();
    for (int c = t; c < BM*8; c += 256) {
      int r = c >> 3, cc = (c & 7) << 3;
      *(s16x8*)&lsA[r][cc] = *(const s16x8*)&A[(size_t)(m0+r)*K + k0 + cc];
    }
    for (int c = t; c < BN*8; c += 256) {
      int r = c >> 3, cc = (c & 7) << 3;
      *(s16x8*)&lsB[r][cc] = *(const s16x8*)&Bt[(size_t)(n0+r)*K + k0 + cc];
    }
    __syncthreads();
    #pragma unroll
    for (int kk = 0; kk < 64; kk += 32) {
      const int ko = kk + (lg << 3);
      s16x8 af[MF], bfr[NF];
      #pragma unroll
      for (int i = 0; i < MF; i++)
        af[i] = *(const s16x8*)&lsA[wm*(BM/2) + i*16 + l15][ko];
      #pragma unroll
      for (int j = 0; j < NF; j++)
        bfr[j] = *(const s16x8*)&lsB[wn*(BN/2) + j*16 + l15][ko];
      #pragma unroll
      for (int i = 0; i < MF; i++)
        #pragma unroll
        for (int j = 0; j < NF; j++)
          acc[i][j] = __builtin_amdgcn_mfma_f32_16x16x32_bf16(af[i], bfr[j], acc[i][j], 0, 0, 0);
    }
  }
  #pragma unroll
  for (int j = 0; j < NF; j++) {
    const int col = n0 + wn*(BN/2) + j*16 + l15;
    const float bv = bias[col];
    #pragma unroll
    for (int i = 0; i < MF; i++) {
      #pragma unroll
      for (int r = 0; r < 4; r++) {
        const int row = m0 + wm*(BM/2) + i*16 + (lg << 2) + r;
        float v = acc[i][j][r] + bv;
        if (ACT == 1) v = gelu_f(v);
        if constexpr (OUT == 0 || OUT == 2) C32[(size_t)row*N + col] = v;
        if constexpr (OUT == 1 || OUT == 2) C16[(size_t)row*N + col] = f2b(v);
      }
    }
  }
}

// ---------------------------------------------------------------- attention
// q,k bf16 with row stride qs; vt bf16 [B*NH][DH][S]; ctx bf16 [B*S][H].
// grid (S/64, B*NH), block 256, XCD-swizzled so q-tiles of one head share L2.
__global__ __launch_bounds__(256)
void attn_fwd(const u16* __restrict__ q, const u16* __restrict__ k,
              const u16* __restrict__ vt, u16* __restrict__ ctx, int qs)
{
  int bx = blockIdx.x, by = blockIdx.y;
  xcd_swz(gridDim.x, gridDim.y, bx, by);
  const int qt = bx, bh = by;
  const int b = bh / NHD, h = bh - b*NHD;
  __shared__ __align__(16) u16 lsK[64][72];
  __shared__ __align__(16) u16 lsV[64][72];
  __shared__ __align__(16) u16 lsP[4][16][72];
  const int t = threadIdx.x, lane = t & 63, w = t >> 6;
  const int l15 = lane & 15, lg = lane >> 4;

  const int qrow = qt*64 + w*16 + l15;
  const size_t qoff = (size_t)(b*SS + qrow)*qs + h*DHD;
  const s16x8 qf0 = *(const s16x8*)&q[qoff + (lg << 3)];
  const s16x8 qf1 = *(const s16x8*)&q[qoff + 32 + (lg << 3)];

  float m_run[4], l_run[4];
  f32x4 oacc[4];
  #pragma unroll
  for (int r = 0; r < 4; r++) { m_run[r] = -1e30f; l_run[r] = 0.f; }
  #pragma unroll
  for (int j = 0; j < 4; j++) oacc[j] = (f32x4){0.f,0.f,0.f,0.f};

  const u16* kbase = k + (size_t)(b*SS)*qs + h*DHD;
  const u16* vbase = vt + (size_t)bh*DHD*SS;

  for (int kt = 0; kt < SS/64; kt++) {
    __syncthreads();
    for (int c = t; c < 512; c += 256) {
      int r = c >> 3, cc = (c & 7) << 3;
      *(s16x8*)&lsK[r][cc] = *(const s16x8*)&kbase[(size_t)(kt*64 + r)*qs + cc];
    }
    for (int c = t; c < 512; c += 256) {
      int r = c >> 3, cc = (c & 7) << 3;
      *(s16x8*)&lsV[r][cc] = *(const s16x8*)&vbase[(size_t)r*SS + kt*64 + cc];
    }
    __syncthreads();

    f32x4 sc[4];
    #pragma unroll
    for (int nf = 0; nf < 4; nf++) sc[nf] = (f32x4){0.f,0.f,0.f,0.f};
    #pragma unroll
    for (int kk = 0; kk < 2; kk++) {
      const int ko = kk*32 + (lg << 3);
      const s16x8 a = kk ? qf1 : qf0;
      #pragma unroll
      for (int nf = 0; nf < 4; nf++) {
        s16x8 kf = *(const s16x8*)&lsK[nf*16 + l15][ko];
        sc[nf] = __builtin_amdgcn_mfma_f32_16x16x32_bf16(a, kf, sc[nf], 0, 0, 0);
      }
    }
    float alpha[4], pv[4][4];
    #pragma unroll
    for (int r = 0; r < 4; r++) {
      float mx = fmaxf(fmaxf(sc[0][r], sc[1][r]), fmaxf(sc[2][r], sc[3][r])) * 0.125f;
      #pragma unroll
      for (int o = 1; o < 16; o <<= 1) mx = fmaxf(mx, __shfl_xor(mx, o, 64));
      const float nm = fmaxf(m_run[r], mx);
      alpha[r] = __expf(m_run[r] - nm);
      float sum = 0.f;
      #pragma unroll
      for (int nf = 0; nf < 4; nf++) {
        float p = __expf(sc[nf][r]*0.125f - nm);
        pv[nf][r] = p; sum += p;
      }
      #pragma unroll
      for (int o = 1; o < 16; o <<= 1) sum += __shfl_xor(sum, o, 64);
      l_run[r] = l_run[r]*alpha[r] + sum;
      m_run[r] = nm;
    }
    #pragma unroll
    for (int j = 0; j < 4; j++) {
      f32x4 o = oacc[j];
      o[0] *= alpha[0]; o[1] *= alpha[1]; o[2] *= alpha[2]; o[3] *= alpha[3];
      oacc[j] = o;
    }
    #pragma unroll
    for (int nf = 0; nf < 4; nf++)
      #pragma unroll
      for (int r = 0; r < 4; r++)
        lsP[w][(lg << 2) + r][nf*16 + l15] = f2b(pv[nf][r]);
    __syncthreads();
    #pragma unroll
    for (int ks = 0; ks < 2; ks++) {
      const int ko = ks*32 + (lg << 3);
      const s16x8 pf = *(const s16x8*)&lsP[w][l15][ko];
      #pragma unroll
      for (int j = 0; j < 4; j++) {
        s16x8 vf = *(const s16x8*)&lsV[j*16 + l15][ko];
        oacc[j] = __builtin_amdgcn_mfma_f32_16x16x32_bf16(pf, vf, oacc[j], 0, 0, 0);
      }
    }
  }
  #pragma unroll
  for (int j = 0; j < 4; j++)
    #pragma unroll
    for (int r = 0; r < 4; r++) {
      const int row = qt*64 + w*16 + (lg << 2) + r;
      ctx[((size_t)(b*SS + row))*HH + h*DHD + j*16 + l15] = f2b(oacc[j][r] / l_run[r]);
    }
}

// ---------------------------------------------------------------- adapter
__global__ __launch_bounds__(256)
void adp_gather(const float* __restrict__ d, const int* __restrict__ nidx,
                const int* __restrict__ eidx, float* __restrict__ esum,
                float* __restrict__ ecnt)
{
  const int gi = blockIdx.x*4 + (threadIdx.x >> 6);
  const int lane = threadIdx.x & 63;
  const int b = gi >> 12, i = gi & (EIC - 1);
  const int n = nidx[(size_t)b*EIC + i];
  const int e = eidx[(size_t)b*EIC + i];
  const float val = d[((size_t)b*SS + n)*RR + lane];
  atomicAdd(&esum[((size_t)b*NEC + e)*RR + lane], val);
  if (lane == 0) atomicAdd(&ecnt[(size_t)b*NEC + e], 1.0f);
}

__global__ __launch_bounds__(256)
void adp_edge(const float* __restrict__ esum, const float* __restrict__ ecnt,
              const int* __restrict__ types, const float* __restrict__ temb,
              float* __restrict__ e_out)
{
  const int ge = blockIdx.x*4 + (threadIdx.x >> 6);
  const int lane = threadIdx.x & 63;
  const int b = ge >> 9, e = ge & (NEC - 1);
  const float cnt = fmaxf(ecnt[(size_t)b*NEC + e], 1.0f);
  const int ty = types[(size_t)b*NEC + e];
  e_out[((size_t)b*NEC + e)*RR + lane] =
      esum[((size_t)b*NEC + e)*RR + lane]/cnt + temb[(size_t)ty*RR + lane];
}

__global__ __launch_bounds__(256)
void adp_scatter(const float* __restrict__ e_out, const int* __restrict__ nidx,
                 const int* __restrict__ eidx, float* __restrict__ nsum,
                 float* __restrict__ ncnt)
{
  const int gi = blockIdx.x*4 + (threadIdx.x >> 6);
  const int lane = threadIdx.x & 63;
  const int b = gi >> 12, i = gi & (EIC - 1);
  const int n = nidx[(size_t)b*EIC + i];
  const int e = eidx[(size_t)b*EIC + i];
  atomicAdd(&nsum[((size_t)b*SS + n)*RR + lane], e_out[((size_t)b*NEC + e)*RR + lane]);
  if (lane == 0) atomicAdd(&ncnt[(size_t)b*SS + n], 1.0f);
}

// out bf16 (feeds adapter-up GEMM A)
__global__ __launch_bounds__(256)
void adp_node(const float* __restrict__ nsum, const float* __restrict__ ncnt,
              u16* __restrict__ u)
{
  const int gn = blockIdx.x*4 + (threadIdx.x >> 6);
  const int lane = threadIdx.x & 63;
  const float cnt = fmaxf(ncnt[gn], 1.0f);
  u[(size_t)gn*RR + lane] = f2b(nsum[(size_t)gn*RR + lane]/cnt);
}

// ---------------------------------------------------------------- layernorm
// out = LN(a+b+c)*g + beta (fp32); optional bf16 copy outb.
__global__ __launch_bounds__(256)
void ln3(const float* __restrict__ a, const float* __restrict__ bb,
         const float* __restrict__ c, const float* __restrict__ g,
         const float* __restrict__ be, float* __restrict__ out,
         u16* __restrict__ outb)
{
  const int row = blockIdx.x, t = threadIdx.x;
  const size_t base = (size_t)row*HH;
  float v[3]; float s = 0.f, s2 = 0.f;
  #pragma unroll
  for (int i = 0; i < 3; i++) {
    int col = t + i*256;
    float x = a[base+col] + bb[base+col] + c[base+col];
    v[i] = x; s += x; s2 += x*x;
  }
  #pragma unroll
  for (int o = 1; o < 64; o <<= 1) { s += __shfl_xor(s, o, 64); s2 += __shfl_xor(s2, o, 64); }
  __shared__ float red[2][4];
  if ((t & 63) == 0) { red[0][t>>6] = s; red[1][t>>6] = s2; }
  __syncthreads();
  const float S  = red[0][0]+red[0][1]+red[0][2]+red[0][3];
  const float S2 = red[1][0]+red[1][1]+red[1][2]+red[1][3];
  const float mean = S*(1.0f/HH);
  const float var  = S2*(1.0f/HH) - mean*mean;
  const float inv  = rsqrtf(var + 1e-5f);
  #pragma unroll
  for (int i = 0; i < 3; i++) {
    int col = t + i*256;
    const float res = (v[i]-mean)*inv*g[col] + be[col];
    out[base+col] = res;
    if (outb) outb[base+col] = f2b(res);
  }
}

// ---------------------------------------------------------------- host
extern "C" void kernel_launch(void* const* d_in, const int* in_sizes, int n_in,
                              void* d_out, int out_size, void* d_ws, size_t ws_size,
                              hipStream_t stream)
{
  (void)in_sizes; (void)n_in; (void)out_size; (void)ws_size;
  const float* x        = (const float*)d_in[0];
  const int* node_idx   = (const int*)d_in[1];
  const int* edge_idx   = (const int*)d_in[2];
  const int* edge_types = (const int*)d_in[3];
  const float* Wq = (const float*)d_in[4];  const float* bq = (const float*)d_in[5];
  const float* Wk = (const float*)d_in[6];  const float* bk = (const float*)d_in[7];
  const float* Wv = (const float*)d_in[8];  const float* bv = (const float*)d_in[9];
  const float* Wo = (const float*)d_in[10]; const float* bo = (const float*)d_in[11];
  const float* ln1_g = (const float*)d_in[12]; const float* ln1_b = (const float*)d_in[13];
  const float* a1_dw = (const float*)d_in[14]; const float* a1_db = (const float*)d_in[15];
  const float* a1_uw = (const float*)d_in[16]; const float* a1_ub = (const float*)d_in[17];
  const float* a1_temb = (const float*)d_in[18];
  const float* Wi  = (const float*)d_in[19]; const float* bi  = (const float*)d_in[20];
  const float* Wd2 = (const float*)d_in[21]; const float* bd2 = (const float*)d_in[22];
  const float* ln2_g = (const float*)d_in[23]; const float* ln2_b = (const float*)d_in[24];
  const float* a2_dw = (const float*)d_in[25]; const float* a2_db = (const float*)d_in[26];
  const float* a2_uw = (const float*)d_in[27]; const float* a2_ub = (const float*)d_in[28];
  const float* a2_temb = (const float*)d_in[29];

  char* ws = (char*)d_ws;
  size_t off = 0;
  auto take = [&](size_t bytes) -> size_t {
    size_t o = off; off += (bytes + 255) & ~(size_t)255; return o;
  };
  const size_t actB2 = (size_t)8192*768*2;   // bf16 [B*S, H]
  const size_t actB4 = (size_t)8192*768*4;   // fp32 [B*S, H]
  const size_t oWqkvT = take(2304ull*768*2);   // rows 0-767 Wq^T, 768-1535 Wk^T, 1536-2303 Wv^T
  const size_t oWoT   = take(768ull*768*2);
  const size_t oWiT   = take(768ull*3072*2);
  const size_t oWd2T  = take(768ull*3072*2);
  const size_t oA1dwT = take(768ull*64*2);
  const size_t oA1uwT = take(768ull*64*2);
  const size_t oA2dwT = take(768ull*64*2);
  const size_t oA2uwT = take(768ull*64*2);
  const size_t oBqkv  = take(2304ull*4);
  const size_t oXbf  = take(actB2);            // x bf16; reused as attn_dense_bf
  const size_t oQkv  = take((size_t)8192*2304*2);   // qkv bf16; +vtb reused as inter
  const size_t oVt   = take(actB2);            // [96][64][1024]
  const size_t oCtx  = take(actB2);            // reused as ffb_bf
  const size_t oAD   = take(actB4);            // attn_dense fp32; reused as ffb fp32
  const size_t oAdp  = take(actB4);            // adapter up out fp32 (shared 1/2)
  const size_t oAO   = take(actB4);            // attn_out fp32
  const size_t oAOb  = take(actB2);            // attn_out bf16 (FFN1 A)
  const size_t oDb   = take((size_t)8192*64*4);
  const size_t oUb   = take((size_t)8192*64*2);
  const size_t oEsum = take((size_t)8*512*64*4);
  const size_t oEcnt = take((size_t)8*512*4);
  const size_t oNsum = take((size_t)8*1024*64*4);
  const size_t oNcnt = take((size_t)8*1024*4);
  const size_t oEbuf = take((size_t)8*512*64*4);
  const size_t oInter = oQkv;   // bf16 [8192][3072] = qkv(37.75MB)+vtb(12.6MB), both dead
  const size_t oFF    = oAD;    // fp32 ff (attn_dense dead after ln1)
  const size_t oFFb   = oCtx;   // bf16 ff copy (ctx dead after O-proj)
  const size_t oADb   = oXbf;   // bf16 attn_dense copy (xbf dead after QKV)
  const size_t zeroBytes = oEbuf - oEsum;

  u16* WqkvT = (u16*)(ws+oWqkvT); u16* WoT = (u16*)(ws+oWoT);
  u16* WiT = (u16*)(ws+oWiT);     u16* Wd2T = (u16*)(ws+oWd2T);
  u16* A1dwT = (u16*)(ws+oA1dwT); u16* A1uwT = (u16*)(ws+oA1uwT);
  u16* A2dwT = (u16*)(ws+oA2dwT); u16* A2uwT = (u16*)(ws+oA2uwT);
  float* bias_qkv = (float*)(ws+oBqkv);
  u16* xbf = (u16*)(ws+oXbf);
  u16* qkv = (u16*)(ws+oQkv);
  u16* vtb = (u16*)(ws+oVt);  u16* ctx = (u16*)(ws+oCtx);
  float* attn_dense = (float*)(ws+oAD); u16* attn_dense_bf = (u16*)(ws+oADb);
  float* adb = (float*)(ws+oAdp);
  float* attn_out = (float*)(ws+oAO);   u16* attn_out_bf = (u16*)(ws+oAOb);
  float* dbuf = (float*)(ws+oDb);       u16* ubuf = (u16*)(ws+oUb);
  float* esum = (float*)(ws+oEsum); float* ecnt = (float*)(ws+oEcnt);
  float* nsum = (float*)(ws+oNsum); float* ncnt = (float*)(ws+oNcnt);
  float* ebuf = (float*)(ws+oEbuf);
  u16* inter = (u16*)(ws+oInter);
  float* ffb = (float*)(ws+oFF);  u16* ffb_bf = (u16*)(ws+oFFb);

  const dim3 blk(256);
  // weight packs (fp32 -> bf16 Bt layout); Wqkv fused
  wtrans<<<dim3(12,12), blk, 0, stream>>>(Wq,  WqkvT,            768, 768);
  wtrans<<<dim3(12,12), blk, 0, stream>>>(Wk,  WqkvT + 768*768,  768, 768);
  wtrans<<<dim3(12,12), blk, 0, stream>>>(Wv,  WqkvT + 2*768*768,768, 768);
  wtrans<<<dim3(12,12), blk, 0, stream>>>(Wo,  WoT,  768, 768);
  wtrans<<<dim3(12,48), blk, 0, stream>>>(Wi,  WiT,  768, 3072);
  wtrans<<<dim3(48,12), blk, 0, stream>>>(Wd2, Wd2T, 3072, 768);
  wtrans<<<dim3(12,1),  blk, 0, stream>>>(a1_dw, A1dwT, 768, 64);
  wtrans<<<dim3(1,12),  blk, 0, stream>>>(a1_uw, A1uwT, 64, 768);
  wtrans<<<dim3(12,1),  blk, 0, stream>>>(a2_dw, A2dwT, 768, 64);
  wtrans<<<dim3(1,12),  blk, 0, stream>>>(a2_uw, A2uwT, 64, 768);
  hipMemcpyAsync(bias_qkv,        bq, 768*4, hipMemcpyDeviceToDevice, stream);
  hipMemcpyAsync(bias_qkv + 768,  bk, 768*4, hipMemcpyDeviceToDevice, stream);
  hipMemcpyAsync(bias_qkv + 1536, bv, 768*4, hipMemcpyDeviceToDevice, stream);
  // x -> bf16 (8192*768/2048 = 3072 blocks)
  cvt16<<<3072, blk, 0, stream>>>(x, xbf);
  // fused QKV: [8192,2304] = xbf @ WqkvT^T
  gemm_bt<64,128,0,1><<<dim3(18,128), blk, 0, stream>>>(xbf, WqkvT, bias_qkv, nullptr, qkv, 8192, 2304, 768);
  vtrans<<<dim3(16,96), blk, 0, stream>>>(qkv + 1536, vtb, 2304);
  attn_fwd<<<dim3(16,96), blk, 0, stream>>>(qkv, qkv + 768, vtb, ctx, 2304);
  gemm_bt<64,128,0,2><<<dim3(6,128), blk, 0, stream>>>(ctx, WoT, bo, attn_dense, attn_dense_bf, 8192, 768, 768);
  // adapter 1 (input attn_dense)
  gemm_bt<64,64,1,0><<<dim3(1,128), blk, 0, stream>>>(attn_dense_bf, A1dwT, a1_db, dbuf, nullptr, 8192, 64, 768);
  hipMemsetAsync(ws + oEsum, 0, zeroBytes, stream);
  adp_gather<<<8192, blk, 0, stream>>>(dbuf, node_idx, edge_idx, esum, ecnt);
  adp_edge<<<1024, blk, 0, stream>>>(esum, ecnt, edge_types, a1_temb, ebuf);
  adp_scatter<<<8192, blk, 0, stream>>>(ebuf, node_idx, edge_idx, nsum, ncnt);
  adp_node<<<2048, blk, 0, stream>>>(nsum, ncnt, ubuf);
  gemm_bt<64,128,0,0><<<dim3(6,128), blk, 0, stream>>>(ubuf, A1uwT, a1_ub, adb, nullptr, 8192, 768, 64);
  ln3<<<8192, blk, 0, stream>>>(attn_dense, adb, x, ln1_g, ln1_b, attn_out, attn_out_bf);
  // FFN
  gemm_bt<64,128,1,1><<<dim3(24,128), blk, 0, stream>>>(attn_out_bf, WiT, bi, nullptr, inter, 8192, 3072, 768);
  gemm_bt<64,128,0,2><<<dim3(6,128), blk, 0, stream>>>(inter, Wd2T, bd2, ffb, ffb_bf, 8192, 768, 3072);
  // adapter 2 (input ff)
  gemm_bt<64,64,1,0><<<dim3(1,128), blk, 0, stream>>>(ffb_bf, A2dwT, a2_db, dbuf, nullptr, 8192, 64, 768);
  hipMemsetAsync(ws + oEsum, 0, zeroBytes, stream);
  adp_gather<<<8192, blk, 0, stream>>>(dbuf, node_idx, edge_idx, esum, ecnt);
  adp_edge<<<1024, blk, 0, stream>>>(esum, ecnt, edge_types, a2_temb, ebuf);
  adp_scatter<<<8192, blk, 0, stream>>>(ebuf, node_idx, edge_idx, nsum, ncnt);
  adp_node<<<2048, blk, 0, stream>>>(nsum, ncnt, ubuf);
  gemm_bt<64,128,0,0><<<dim3(6,128), blk, 0, stream>>>(ubuf, A2uwT, a2_ub, adb, nullptr, 8192, 768, 64);
  // final LN -> d_out (fp32)
  ln3<<<8192, blk, 0, stream>>>(ffb, adb, attn_out, ln2_g, ln2_b, (float*)d_out, nullptr);
}

// Round 8
// 629.102 us; speedup vs baseline: 1.6695x; 1.2873x over previous
//
#include <hip/hip_runtime.h>

typedef unsigned short u16;
typedef __attribute__((ext_vector_type(8))) short s16x8;
typedef __attribute__((ext_vector_type(4))) float f32x4;
typedef __attribute__((ext_vector_type(4))) unsigned short u16x4;

#define NB 8
#define SS 1024
#define HH 768
#define NHD 12
#define DHD 64
#define FFD 3072
#define RR 64
#define NEC 512
#define EIC 4096

__device__ __forceinline__ float b2f(u16 u){ return __uint_as_float(((unsigned)u)<<16); }
__device__ __forceinline__ u16 f2b(float f){
  unsigned x = __float_as_uint(f);
  return (u16)((x + 0x7fffu + ((x>>16)&1u)) >> 16);   // RNE
}
__device__ __forceinline__ float gelu_f(float x){
  return 0.5f*x*(1.0f + tanhf(0.79788456080286535588f*(x + 0.044715f*x*x*x)));
}
// bijective XCD-chunked swizzle (m204)
__device__ __forceinline__ void xcd_swz(int gx, int gy, int& bx, int& by){
  const int nwg = gx*gy;
  const int flat = by*gx + bx;
  const int qch = nwg >> 3, rch = nwg & 7;
  const int xcd = flat & 7, idx = flat >> 3;
  const int swz = (xcd < rch ? xcd*(qch+1) : rch*(qch+1) + (xcd-rch)*qch) + idx;
  bx = swz % gx; by = swz / gx;
}

// ---------------------------------------------------------------- fp32->bf16
__global__ __launch_bounds__(256)
void cvt16(const float* __restrict__ src, u16* __restrict__ dst)
{
  const size_t i = ((size_t)blockIdx.x*256 + threadIdx.x)*8;
  float4 a = *(const float4*)&src[i];
  float4 b = *(const float4*)&src[i+4];
  u16x4 h1; h1.x=f2b(a.x); h1.y=f2b(a.y); h1.z=f2b(a.z); h1.w=f2b(a.w);
  u16x4 h2; h2.x=f2b(b.x); h2.y=f2b(b.y); h2.z=f2b(b.z); h2.w=f2b(b.w);
  *(u16x4*)&dst[i] = h1; *(u16x4*)&dst[i+4] = h2;
}

// ---------------------------------------------------------------- transpose
// dst[c][r] = bf16(src[r][c]); src fp32. grid (R/64, C/64), block 256.
__global__ __launch_bounds__(256)
void wtrans(const float* __restrict__ src, u16* __restrict__ dst, int R, int C)
{
  __shared__ u16 tile[64][68];
  const int r0 = blockIdx.x*64, c0 = blockIdx.y*64;
  const int t = threadIdx.x;
  const int tr = t >> 4, tc = (t & 15) * 4;
  for (int i = 0; i < 4; i++) {
    int r = tr + i*16;
    float4 v4 = *(const float4*)&src[(size_t)(r0+r)*C + c0 + tc];
    u16x4 h; h.x = f2b(v4.x); h.y = f2b(v4.y); h.z = f2b(v4.z); h.w = f2b(v4.w);
    *(u16x4*)&tile[r][tc] = h;
  }
  __syncthreads();
  for (int i = 0; i < 4; i++) {
    int rr = tr + i*16;
    u16x4 v;
    v.x = tile[tc+0][rr]; v.y = tile[tc+1][rr];
    v.z = tile[tc+2][rr]; v.w = tile[tc+3][rr];
    *(u16x4*)&dst[(size_t)(c0+rr)*R + r0 + tc] = v;
  }
}

// V (bf16, row stride vs) -> Vt [B*NH][DH][S]. grid (S/64, B*NH), block 256.
__global__ __launch_bounds__(256)
void vtrans(const u16* __restrict__ v, u16* __restrict__ vt, int vs)
{
  __shared__ u16 tile[64][68];
  const int st = blockIdx.x, bh = blockIdx.y;
  const int b = bh / NHD, h = bh - b*NHD;
  const u16* src = v + (size_t)(b*SS + st*64)*vs + h*DHD;
  u16* dst = vt + (size_t)bh*DHD*SS + st*64;
  const int t = threadIdx.x;
  const int tr = t >> 4, tc = (t & 15) * 4;
  for (int i = 0; i < 4; i++) {
    int r = tr + i*16;
    *(u16x4*)&tile[r][tc] = *(const u16x4*)&src[(size_t)r*vs + tc];
  }
  __syncthreads();
  for (int i = 0; i < 4; i++) {
    int rr = tr + i*16;
    u16x4 vv;
    vv.x = tile[tc+0][rr]; vv.y = tile[tc+1][rr];
    vv.z = tile[tc+2][rr]; vv.w = tile[tc+3][rr];
    *(u16x4*)&dst[(size_t)rr*SS + tc] = vv;
  }
}

// ---------------------------------------------------------------- GEMM
// C = act(A[M,K](bf16) @ Bt[N,K]^T + bias). BK=64, 4 waves (2x2).
// Staging: global_load_lds 16B/lane, LINEAR LDS dest, source pre-swizzled
// chunk^=(row&7); ds_read applies the same XOR (rule #21 both-sides swizzle).
// OUT: 0 = fp32 only, 1 = bf16 only, 2 = both. grid (N/BN, M/BM), XCD-swizzled.
template<int BM, int BN, int ACT, int OUT>
__global__ __launch_bounds__(256)
void gemm_bt(const u16* __restrict__ A, const u16* __restrict__ Bt,
             const float* __restrict__ bias, float* __restrict__ C32,
             u16* __restrict__ C16, int M, int N, int K)
{
  constexpr int MF = BM/32;
  constexpr int NF = BN/32;
  __shared__ __align__(16) u16 lsA[BM*64];
  __shared__ __align__(16) u16 lsB[BN*64];
  int bx = blockIdx.x, by = blockIdx.y;
  xcd_swz(gridDim.x, gridDim.y, bx, by);
  const int m0 = by*BM, n0 = bx*BN;
  const int t = threadIdx.x, lane = t & 63, w = t >> 6;
  const int wm = w >> 1, wn = w & 1;
  const int l15 = lane & 15, lg = lane >> 4;

  f32x4 acc[MF][NF];
  #pragma unroll
  for (int i = 0; i < MF; i++)
    #pragma unroll
    for (int j = 0; j < NF; j++) acc[i][j] = (f32x4){0.f,0.f,0.f,0.f};

  for (int k0 = 0; k0 < K; k0 += 64) {
    __syncthreads();
    // stage A: BM rows x 128B; one instr = wave covers 64 chunks of 16B
    #pragma unroll
    for (int i = 0; i < BM/32; i++) {
      const int p = (w*(BM/32) + i)*64 + lane;        // 16B-chunk position
      const int r = p >> 3;
      const int ch = (p & 7) ^ (r & 7);               // pre-swizzled source chunk
      __builtin_amdgcn_global_load_lds(
        (const __attribute__((address_space(1))) unsigned*)(A + (size_t)(m0+r)*K + k0 + ch*8),
        (__attribute__((address_space(3))) unsigned*)(lsA + (w*(BM/32)+i)*512),
        16, 0, 0);
    }
    #pragma unroll
    for (int i = 0; i < BN/32; i++) {
      const int p = (w*(BN/32) + i)*64 + lane;
      const int r = p >> 3;
      const int ch = (p & 7) ^ (r & 7);
      __builtin_amdgcn_global_load_lds(
        (const __attribute__((address_space(1))) unsigned*)(Bt + (size_t)(n0+r)*K + k0 + ch*8),
        (__attribute__((address_space(3))) unsigned*)(lsB + (w*(BN/32)+i)*512),
        16, 0, 0);
    }
    __syncthreads();
    #pragma unroll
    for (int kk = 0; kk < 64; kk += 32) {
      const int cb = (kk >> 3) + lg;                  // global chunk wanted
      s16x8 af[MF], bfr[NF];
      #pragma unroll
      for (int i = 0; i < MF; i++) {
        const int row = wm*(BM/2) + i*16 + l15;
        af[i] = *(const s16x8*)&lsA[row*64 + ((cb ^ (row & 7)) << 3)];
      }
      #pragma unroll
      for (int j = 0; j < NF; j++) {
        const int row = wn*(BN/2) + j*16 + l15;
        bfr[j] = *(const s16x8*)&lsB[row*64 + ((cb ^ (row & 7)) << 3)];
      }
      #pragma unroll
      for (int i = 0; i < MF; i++)
        #pragma unroll
        for (int j = 0; j < NF; j++)
          acc[i][j] = __builtin_amdgcn_mfma_f32_16x16x32_bf16(af[i], bfr[j], acc[i][j], 0, 0, 0);
    }
  }
  #pragma unroll
  for (int j = 0; j < NF; j++) {
    const int col = n0 + wn*(BN/2) + j*16 + l15;
    const float bv = bias[col];
    #pragma unroll
    for (int i = 0; i < MF; i++) {
      #pragma unroll
      for (int r = 0; r < 4; r++) {
        const int row = m0 + wm*(BM/2) + i*16 + (lg << 2) + r;
        float v = acc[i][j][r] + bv;
        if (ACT == 1) v = gelu_f(v);
        if constexpr (OUT == 0 || OUT == 2) C32[(size_t)row*N + col] = v;
        if constexpr (OUT == 1 || OUT == 2) C16[(size_t)row*N + col] = f2b(v);
      }
    }
  }
}

// ---------------------------------------------------------------- attention
__global__ __launch_bounds__(256)
void attn_fwd(const u16* __restrict__ q, const u16* __restrict__ k,
              const u16* __restrict__ vt, u16* __restrict__ ctx, int qs)
{
  int bx = blockIdx.x, by = blockIdx.y;
  xcd_swz(gridDim.x, gridDim.y, bx, by);
  const int qt = bx, bh = by;
  const int b = bh / NHD, h = bh - b*NHD;
  __shared__ __align__(16) u16 lsK[64][72];
  __shared__ __align__(16) u16 lsV[64][72];
  __shared__ __align__(16) u16 lsP[4][16][72];
  const int t = threadIdx.x, lane = t & 63, w = t >> 6;
  const int l15 = lane & 15, lg = lane >> 4;

  const int qrow = qt*64 + w*16 + l15;
  const size_t qoff = (size_t)(b*SS + qrow)*qs + h*DHD;
  const s16x8 qf0 = *(const s16x8*)&q[qoff + (lg << 3)];
  const s16x8 qf1 = *(const s16x8*)&q[qoff + 32 + (lg << 3)];

  float m_run[4], l_run[4];
  f32x4 oacc[4];
  #pragma unroll
  for (int r = 0; r < 4; r++) { m_run[r] = -1e30f; l_run[r] = 0.f; }
  #pragma unroll
  for (int j = 0; j < 4; j++) oacc[j] = (f32x4){0.f,0.f,0.f,0.f};

  const u16* kbase = k + (size_t)(b*SS)*qs + h*DHD;
  const u16* vbase = vt + (size_t)bh*DHD*SS;

  for (int kt = 0; kt < SS/64; kt++) {
    __syncthreads();
    for (int c = t; c < 512; c += 256) {
      int r = c >> 3, cc = (c & 7) << 3;
      *(s16x8*)&lsK[r][cc] = *(const s16x8*)&kbase[(size_t)(kt*64 + r)*qs + cc];
    }
    for (int c = t; c < 512; c += 256) {
      int r = c >> 3, cc = (c & 7) << 3;
      *(s16x8*)&lsV[r][cc] = *(const s16x8*)&vbase[(size_t)r*SS + kt*64 + cc];
    }
    __syncthreads();

    f32x4 sc[4];
    #pragma unroll
    for (int nf = 0; nf < 4; nf++) sc[nf] = (f32x4){0.f,0.f,0.f,0.f};
    #pragma unroll
    for (int kk = 0; kk < 2; kk++) {
      const int ko = kk*32 + (lg << 3);
      const s16x8 a = kk ? qf1 : qf0;
      #pragma unroll
      for (int nf = 0; nf < 4; nf++) {
        s16x8 kf = *(const s16x8*)&lsK[nf*16 + l15][ko];
        sc[nf] = __builtin_amdgcn_mfma_f32_16x16x32_bf16(a, kf, sc[nf], 0, 0, 0);
      }
    }
    float alpha[4], pv[4][4];
    #pragma unroll
    for (int r = 0; r < 4; r++) {
      float mx = fmaxf(fmaxf(sc[0][r], sc[1][r]), fmaxf(sc[2][r], sc[3][r])) * 0.125f;
      #pragma unroll
      for (int o = 1; o < 16; o <<= 1) mx = fmaxf(mx, __shfl_xor(mx, o, 64));
      const float nm = fmaxf(m_run[r], mx);
      alpha[r] = __expf(m_run[r] - nm);
      float sum = 0.f;
      #pragma unroll
      for (int nf = 0; nf < 4; nf++) {
        float p = __expf(sc[nf][r]*0.125f - nm);
        pv[nf][r] = p; sum += p;
      }
      #pragma unroll
      for (int o = 1; o < 16; o <<= 1) sum += __shfl_xor(sum, o, 64);
      l_run[r] = l_run[r]*alpha[r] + sum;
      m_run[r] = nm;
    }
    #pragma unroll
    for (int j = 0; j < 4; j++) {
      f32x4 o = oacc[j];
      o[0] *= alpha[0]; o[1] *= alpha[1]; o[2] *= alpha[2]; o[3] *= alpha[3];
      oacc[j] = o;
    }
    #pragma unroll
    for (int nf = 0; nf < 4; nf++)
      #pragma unroll
      for (int r = 0; r < 4; r++)
        lsP[w][(lg << 2) + r][nf*16 + l15] = f2b(pv[nf][r]);
    __syncthreads();
    #pragma unroll
    for (int ks = 0; ks < 2; ks++) {
      const int ko = ks*32 + (lg << 3);
      const s16x8 pf = *(const s16x8*)&lsP[w][l15][ko];
      #pragma unroll
      for (int j = 0; j < 4; j++) {
        s16x8 vf = *(const s16x8*)&lsV[j*16 + l15][ko];
        oacc[j] = __builtin_amdgcn_mfma_f32_16x16x32_bf16(pf, vf, oacc[j], 0, 0, 0);
      }
    }
  }
  #pragma unroll
  for (int j = 0; j < 4; j++)
    #pragma unroll
    for (int r = 0; r < 4; r++) {
      const int row = qt*64 + w*16 + (lg << 2) + r;
      ctx[((size_t)(b*SS + row))*HH + h*DHD + j*16 + l15] = f2b(oacc[j][r] / l_run[r]);
    }
}

// ---------------------------------------------------------------- adapter
__global__ __launch_bounds__(256)
void adp_gather(const float* __restrict__ d, const int* __restrict__ nidx,
                const int* __restrict__ eidx, float* __restrict__ esum,
                float* __restrict__ ecnt)
{
  const int gi = blockIdx.x*4 + (threadIdx.x >> 6);
  const int lane = threadIdx.x & 63;
  const int b = gi >> 12, i = gi & (EIC - 1);
  const int n = nidx[(size_t)b*EIC + i];
  const int e = eidx[(size_t)b*EIC + i];
  const float val = d[((size_t)b*SS + n)*RR + lane];
  atomicAdd(&esum[((size_t)b*NEC + e)*RR + lane], val);
  if (lane == 0) atomicAdd(&ecnt[(size_t)b*NEC + e], 1.0f);
}

__global__ __launch_bounds__(256)
void adp_edge(const float* __restrict__ esum, const float* __restrict__ ecnt,
              const int* __restrict__ types, const float* __restrict__ temb,
              float* __restrict__ e_out)
{
  const int ge = blockIdx.x*4 + (threadIdx.x >> 6);
  const int lane = threadIdx.x & 63;
  const int b = ge >> 9, e = ge & (NEC - 1);
  const float cnt = fmaxf(ecnt[(size_t)b*NEC + e], 1.0f);
  const int ty = types[(size_t)b*NEC + e];
  e_out[((size_t)b*NEC + e)*RR + lane] =
      esum[((size_t)b*NEC + e)*RR + lane]/cnt + temb[(size_t)ty*RR + lane];
}

__global__ __launch_bounds__(256)
void adp_scatter(const float* __restrict__ e_out, const int* __restrict__ nidx,
                 const int* __restrict__ eidx, float* __restrict__ nsum,
                 float* __restrict__ ncnt)
{
  const int gi = blockIdx.x*4 + (threadIdx.x >> 6);
  const int lane = threadIdx.x & 63;
  const int b = gi >> 12, i = gi & (EIC - 1);
  const int n = nidx[(size_t)b*EIC + i];
  const int e = eidx[(size_t)b*EIC + i];
  atomicAdd(&nsum[((size_t)b*SS + n)*RR + lane], e_out[((size_t)b*NEC + e)*RR + lane]);
  if (lane == 0) atomicAdd(&ncnt[(size_t)b*SS + n], 1.0f);
}

__global__ __launch_bounds__(256)
void adp_node(const float* __restrict__ nsum, const float* __restrict__ ncnt,
              u16* __restrict__ u)
{
  const int gn = blockIdx.x*4 + (threadIdx.x >> 6);
  const int lane = threadIdx.x & 63;
  const float cnt = fmaxf(ncnt[gn], 1.0f);
  u[(size_t)gn*RR + lane] = f2b(nsum[(size_t)gn*RR + lane]/cnt);
}

// ---------------------------------------------------------------- layernorm
__global__ __launch_bounds__(256)
void ln3(const float* __restrict__ a, const float* __restrict__ bb,
         const float* __restrict__ c, const float* __restrict__ g,
         const float* __restrict__ be, float* __restrict__ out,
         u16* __restrict__ outb)
{
  const int row = blockIdx.x, t = threadIdx.x;
  const size_t base = (size_t)row*HH;
  float v[3]; float s = 0.f, s2 = 0.f;
  #pragma unroll
  for (int i = 0; i < 3; i++) {
    int col = t + i*256;
    float x = a[base+col] + bb[base+col] + c[base+col];
    v[i] = x; s += x; s2 += x*x;
  }
  #pragma unroll
  for (int o = 1; o < 64; o <<= 1) { s += __shfl_xor(s, o, 64); s2 += __shfl_xor(s2, o, 64); }
  __shared__ float red[2][4];
  if ((t & 63) == 0) { red[0][t>>6] = s; red[1][t>>6] = s2; }
  __syncthreads();
  const float S  = red[0][0]+red[0][1]+red[0][2]+red[0][3];
  const float S2 = red[1][0]+red[1][1]+red[1][2]+red[1][3];
  const float mean = S*(1.0f/HH);
  const float var  = S2*(1.0f/HH) - mean*mean;
  const float inv  = rsqrtf(var + 1e-5f);
  #pragma unroll
  for (int i = 0; i < 3; i++) {
    int col = t + i*256;
    const float res = (v[i]-mean)*inv*g[col] + be[col];
    out[base+col] = res;
    if (outb) outb[base+col] = f2b(res);
  }
}

// ---------------------------------------------------------------- host
extern "C" void kernel_launch(void* const* d_in, const int* in_sizes, int n_in,
                              void* d_out, int out_size, void* d_ws, size_t ws_size,
                              hipStream_t stream)
{
  (void)in_sizes; (void)n_in; (void)out_size; (void)ws_size;
  const float* x        = (const float*)d_in[0];
  const int* node_idx   = (const int*)d_in[1];
  const int* edge_idx   = (const int*)d_in[2];
  const int* edge_types = (const int*)d_in[3];
  const float* Wq = (const float*)d_in[4];  const float* bq = (const float*)d_in[5];
  const float* Wk = (const float*)d_in[6];  const float* bk = (const float*)d_in[7];
  const float* Wv = (const float*)d_in[8];  const float* bv = (const float*)d_in[9];
  const float* Wo = (const float*)d_in[10]; const float* bo = (const float*)d_in[11];
  const float* ln1_g = (const float*)d_in[12]; const float* ln1_b = (const float*)d_in[13];
  const float* a1_dw = (const float*)d_in[14]; const float* a1_db = (const float*)d_in[15];
  const float* a1_uw = (const float*)d_in[16]; const float* a1_ub = (const float*)d_in[17];
  const float* a1_temb = (const float*)d_in[18];
  const float* Wi  = (const float*)d_in[19]; const float* bi  = (const float*)d_in[20];
  const float* Wd2 = (const float*)d_in[21]; const float* bd2 = (const float*)d_in[22];
  const float* ln2_g = (const float*)d_in[23]; const float* ln2_b = (const float*)d_in[24];
  const float* a2_dw = (const float*)d_in[25]; const float* a2_db = (const float*)d_in[26];
  const float* a2_uw = (const float*)d_in[27]; const float* a2_ub = (const float*)d_in[28];
  const float* a2_temb = (const float*)d_in[29];

  char* ws = (char*)d_ws;
  size_t off = 0;
  auto take = [&](size_t bytes) -> size_t {
    size_t o = off; off += (bytes + 255) & ~(size_t)255; return o;
  };
  const size_t actB2 = (size_t)8192*768*2;
  const size_t actB4 = (size_t)8192*768*4;
  const size_t oWqkvT = take(2304ull*768*2);
  const size_t oWoT   = take(768ull*768*2);
  const size_t oWiT   = take(768ull*3072*2);
  const size_t oWd2T  = take(768ull*3072*2);
  const size_t oA1dwT = take(768ull*64*2);
  const size_t oA1uwT = take(768ull*64*2);
  const size_t oA2dwT = take(768ull*64*2);
  const size_t oA2uwT = take(768ull*64*2);
  const size_t oBqkv  = take(2304ull*4);
  const size_t oXbf  = take(actB2);
  const size_t oQkv  = take((size_t)8192*2304*2);
  const size_t oVt   = take(actB2);
  const size_t oCtx  = take(actB2);
  const size_t oAD   = take(actB4);
  const size_t oAdp  = take(actB4);
  const size_t oAO   = take(actB4);
  const size_t oAOb  = take(actB2);
  const size_t oDb   = take((size_t)8192*64*4);
  const size_t oUb   = take((size_t)8192*64*2);
  const size_t oEsum = take((size_t)8*512*64*4);
  const size_t oEcnt = take((size_t)8*512*4);
  const size_t oNsum = take((size_t)8*1024*64*4);
  const size_t oNcnt = take((size_t)8*1024*4);
  const size_t oEbuf = take((size_t)8*512*64*4);
  const size_t oInter = oQkv;
  const size_t oFF    = oAD;
  const size_t oFFb   = oCtx;
  const size_t oADb   = oXbf;
  const size_t zeroBytes = oEbuf - oEsum;

  u16* WqkvT = (u16*)(ws+oWqkvT); u16* WoT = (u16*)(ws+oWoT);
  u16* WiT = (u16*)(ws+oWiT);     u16* Wd2T = (u16*)(ws+oWd2T);
  u16* A1dwT = (u16*)(ws+oA1dwT); u16* A1uwT = (u16*)(ws+oA1uwT);
  u16* A2dwT = (u16*)(ws+oA2dwT); u16* A2uwT = (u16*)(ws+oA2uwT);
  float* bias_qkv = (float*)(ws+oBqkv);
  u16* xbf = (u16*)(ws+oXbf);
  u16* qkv = (u16*)(ws+oQkv);
  u16* vtb = (u16*)(ws+oVt);  u16* ctx = (u16*)(ws+oCtx);
  float* attn_dense = (float*)(ws+oAD); u16* attn_dense_bf = (u16*)(ws+oADb);
  float* adb = (float*)(ws+oAdp);
  float* attn_out = (float*)(ws+oAO);   u16* attn_out_bf = (u16*)(ws+oAOb);
  float* dbuf = (float*)(ws+oDb);       u16* ubuf = (u16*)(ws+oUb);
  float* esum = (float*)(ws+oEsum); float* ecnt = (float*)(ws+oEcnt);
  float* nsum = (float*)(ws+oNsum); float* ncnt = (float*)(ws+oNcnt);
  float* ebuf = (float*)(ws+oEbuf);
  u16* inter = (u16*)(ws+oInter);
  float* ffb = (float*)(ws+oFF);  u16* ffb_bf = (u16*)(ws+oFFb);

  const dim3 blk(256);
  wtrans<<<dim3(12,12), blk, 0, stream>>>(Wq,  WqkvT,            768, 768);
  wtrans<<<dim3(12,12), blk, 0, stream>>>(Wk,  WqkvT + 768*768,  768, 768);
  wtrans<<<dim3(12,12), blk, 0, stream>>>(Wv,  WqkvT + 2*768*768,768, 768);
  wtrans<<<dim3(12,12), blk, 0, stream>>>(Wo,  WoT,  768, 768);
  wtrans<<<dim3(12,48), blk, 0, stream>>>(Wi,  WiT,  768, 3072);
  wtrans<<<dim3(48,12), blk, 0, stream>>>(Wd2, Wd2T, 3072, 768);
  wtrans<<<dim3(12,1),  blk, 0, stream>>>(a1_dw, A1dwT, 768, 64);
  wtrans<<<dim3(1,12),  blk, 0, stream>>>(a1_uw, A1uwT, 64, 768);
  wtrans<<<dim3(12,1),  blk, 0, stream>>>(a2_dw, A2dwT, 768, 64);
  wtrans<<<dim3(1,12),  blk, 0, stream>>>(a2_uw, A2uwT, 64, 768);
  hipMemcpyAsync(bias_qkv,        bq, 768*4, hipMemcpyDeviceToDevice, stream);
  hipMemcpyAsync(bias_qkv + 768,  bk, 768*4, hipMemcpyDeviceToDevice, stream);
  hipMemcpyAsync(bias_qkv + 1536, bv, 768*4, hipMemcpyDeviceToDevice, stream);
  cvt16<<<3072, blk, 0, stream>>>(x, xbf);
  // fused QKV
  gemm_bt<64,128,0,1><<<dim3(18,128), blk, 0, stream>>>(xbf, WqkvT, bias_qkv, nullptr, qkv, 8192, 2304, 768);
  vtrans<<<dim3(16,96), blk, 0, stream>>>(qkv + 1536, vtb, 2304);
  attn_fwd<<<dim3(16,96), blk, 0, stream>>>(qkv, qkv + 768, vtb, ctx, 2304);
  gemm_bt<64,128,0,2><<<dim3(6,128), blk, 0, stream>>>(ctx, WoT, bo, attn_dense, attn_dense_bf, 8192, 768, 768);
  // adapter 1
  gemm_bt<64,64,1,0><<<dim3(1,128), blk, 0, stream>>>(attn_dense_bf, A1dwT, a1_db, dbuf, nullptr, 8192, 64, 768);
  hipMemsetAsync(ws + oEsum, 0, zeroBytes, stream);
  adp_gather<<<8192, blk, 0, stream>>>(dbuf, node_idx, edge_idx, esum, ecnt);
  adp_edge<<<1024, blk, 0, stream>>>(esum, ecnt, edge_types, a1_temb, ebuf);
  adp_scatter<<<8192, blk, 0, stream>>>(ebuf, node_idx, edge_idx, nsum, ncnt);
  adp_node<<<2048, blk, 0, stream>>>(nsum, ncnt, ubuf);
  gemm_bt<64,128,0,0><<<dim3(6,128), blk, 0, stream>>>(ubuf, A1uwT, a1_ub, adb, nullptr, 8192, 768, 64);
  ln3<<<8192, blk, 0, stream>>>(attn_dense, adb, x, ln1_g, ln1_b, attn_out, attn_out_bf);
  // FFN
  gemm_bt<64,128,1,1><<<dim3(24,128), blk, 0, stream>>>(attn_out_bf, WiT, bi, nullptr, inter, 8192, 3072, 768);
  gemm_bt<64,128,0,2><<<dim3(6,128), blk, 0, stream>>>(inter, Wd2T, bd2, ffb, ffb_bf, 8192, 768, 3072);
  // adapter 2
  gemm_bt<64,64,1,0><<<dim3(1,128), blk, 0, stream>>>(ffb_bf, A2dwT, a2_db, dbuf, nullptr, 8192, 64, 768);
  hipMemsetAsync(ws + oEsum, 0, zeroBytes, stream);
  adp_gather<<<8192, blk, 0, stream>>>(dbuf, node_idx, edge_idx, esum, ecnt);
  adp_edge<<<1024, blk, 0, stream>>>(esum, ecnt, edge_types, a2_temb, ebuf);
  adp_scatter<<<8192, blk, 0, stream>>>(ebuf, node_idx, edge_idx, nsum, ncnt);
  adp_node<<<2048, blk, 0, stream>>>(nsum, ncnt, ubuf);
  gemm_bt<64,128,0,0><<<dim3(6,128), blk, 0, stream>>>(ubuf, A2uwT, a2_ub, adb, nullptr, 8192, 768, 64);
  ln3<<<8192, blk, 0, stream>>>(ffb, adb, attn_out, ln2_g, ln2_b, (float*)d_out, nullptr);
}

// Round 9
// 584.044 us; speedup vs baseline: 1.7983x; 1.0771x over previous
//
#include <hip/hip_runtime.h>

typedef unsigned short u16;
typedef __attribute__((ext_vector_type(8))) short s16x8;
typedef __attribute__((ext_vector_type(4))) float f32x4;
typedef __attribute__((ext_vector_type(4))) unsigned short u16x4;

#define NB 8
#define SS 1024
#define HH 768
#define NHD 12
#define DHD 64
#define FFD 3072
#define RR 64
#define NEC 512
#define EIC 4096

__device__ __forceinline__ float b2f(u16 u){ return __uint_as_float(((unsigned)u)<<16); }
__device__ __forceinline__ u16 f2b(float f){
  unsigned x = __float_as_uint(f);
  return (u16)((x + 0x7fffu + ((x>>16)&1u)) >> 16);   // RNE
}
__device__ __forceinline__ float gelu_f(float x){
  return 0.5f*x*(1.0f + tanhf(0.79788456080286535588f*(x + 0.044715f*x*x*x)));
}
// bijective XCD-chunked swizzle (m204)
__device__ __forceinline__ void xcd_swz(int gx, int gy, int& bx, int& by){
  const int nwg = gx*gy;
  const int flat = by*gx + bx;
  const int qch = nwg >> 3, rch = nwg & 7;
  const int xcd = flat & 7, idx = flat >> 3;
  const int swz = (xcd < rch ? xcd*(qch+1) : rch*(qch+1) + (xcd-rch)*qch) + idx;
  bx = swz % gx; by = swz / gx;
}

// ---------------------------------------------------------------- fp32->bf16
__global__ __launch_bounds__(256)
void cvt16(const float* __restrict__ src, u16* __restrict__ dst)
{
  const size_t i = ((size_t)blockIdx.x*256 + threadIdx.x)*8;
  float4 a = *(const float4*)&src[i];
  float4 b = *(const float4*)&src[i+4];
  u16x4 h1; h1.x=f2b(a.x); h1.y=f2b(a.y); h1.z=f2b(a.z); h1.w=f2b(a.w);
  u16x4 h2; h2.x=f2b(b.x); h2.y=f2b(b.y); h2.z=f2b(b.z); h2.w=f2b(b.w);
  *(u16x4*)&dst[i] = h1; *(u16x4*)&dst[i+4] = h2;
}

// ---------------------------------------------------------------- transpose
__global__ __launch_bounds__(256)
void wtrans(const float* __restrict__ src, u16* __restrict__ dst, int R, int C)
{
  __shared__ u16 tile[64][68];
  const int r0 = blockIdx.x*64, c0 = blockIdx.y*64;
  const int t = threadIdx.x;
  const int tr = t >> 4, tc = (t & 15) * 4;
  for (int i = 0; i < 4; i++) {
    int r = tr + i*16;
    float4 v4 = *(const float4*)&src[(size_t)(r0+r)*C + c0 + tc];
    u16x4 h; h.x = f2b(v4.x); h.y = f2b(v4.y); h.z = f2b(v4.z); h.w = f2b(v4.w);
    *(u16x4*)&tile[r][tc] = h;
  }
  __syncthreads();
  for (int i = 0; i < 4; i++) {
    int rr = tr + i*16;
    u16x4 v;
    v.x = tile[tc+0][rr]; v.y = tile[tc+1][rr];
    v.z = tile[tc+2][rr]; v.w = tile[tc+3][rr];
    *(u16x4*)&dst[(size_t)(c0+rr)*R + r0 + tc] = v;
  }
}

// V (bf16, row stride vs) -> Vt [B*NH][DH][S]. grid (S/64, B*NH), block 256.
__global__ __launch_bounds__(256)
void vtrans(const u16* __restrict__ v, u16* __restrict__ vt, int vs)
{
  __shared__ u16 tile[64][68];
  const int st = blockIdx.x, bh = blockIdx.y;
  const int b = bh / NHD, h = bh - b*NHD;
  const u16* src = v + (size_t)(b*SS + st*64)*vs + h*DHD;
  u16* dst = vt + (size_t)bh*DHD*SS + st*64;
  const int t = threadIdx.x;
  const int tr = t >> 4, tc = (t & 15) * 4;
  for (int i = 0; i < 4; i++) {
    int r = tr + i*16;
    *(u16x4*)&tile[r][tc] = *(const u16x4*)&src[(size_t)r*vs + tc];
  }
  __syncthreads();
  for (int i = 0; i < 4; i++) {
    int rr = tr + i*16;
    u16x4 vv;
    vv.x = tile[tc+0][rr]; vv.y = tile[tc+1][rr];
    vv.z = tile[tc+2][rr]; vv.w = tile[tc+3][rr];
    *(u16x4*)&dst[(size_t)rr*SS + tc] = vv;
  }
}

// ---------------------------------------------------------------- GEMM
// Staging: global_load_lds 16B/lane, linear LDS dest, both-sides chunk XOR.
template<int BM, int BN, int ACT, int OUT>
__global__ __launch_bounds__(256)
void gemm_bt(const u16* __restrict__ A, const u16* __restrict__ Bt,
             const float* __restrict__ bias, float* __restrict__ C32,
             u16* __restrict__ C16, int M, int N, int K)
{
  constexpr int MF = BM/32;
  constexpr int NF = BN/32;
  __shared__ __align__(16) u16 lsA[BM*64];
  __shared__ __align__(16) u16 lsB[BN*64];
  int bx = blockIdx.x, by = blockIdx.y;
  xcd_swz(gridDim.x, gridDim.y, bx, by);
  const int m0 = by*BM, n0 = bx*BN;
  const int t = threadIdx.x, lane = t & 63, w = t >> 6;
  const int wm = w >> 1, wn = w & 1;
  const int l15 = lane & 15, lg = lane >> 4;

  f32x4 acc[MF][NF];
  #pragma unroll
  for (int i = 0; i < MF; i++)
    #pragma unroll
    for (int j = 0; j < NF; j++) acc[i][j] = (f32x4){0.f,0.f,0.f,0.f};

  for (int k0 = 0; k0 < K; k0 += 64) {
    __syncthreads();
    #pragma unroll
    for (int i = 0; i < BM/32; i++) {
      const int p = (w*(BM/32) + i)*64 + lane;
      const int r = p >> 3;
      const int ch = (p & 7) ^ (r & 7);
      __builtin_amdgcn_global_load_lds(
        (const __attribute__((address_space(1))) unsigned*)(A + (size_t)(m0+r)*K + k0 + ch*8),
        (__attribute__((address_space(3))) unsigned*)(lsA + (w*(BM/32)+i)*512),
        16, 0, 0);
    }
    #pragma unroll
    for (int i = 0; i < BN/32; i++) {
      const int p = (w*(BN/32) + i)*64 + lane;
      const int r = p >> 3;
      const int ch = (p & 7) ^ (r & 7);
      __builtin_amdgcn_global_load_lds(
        (const __attribute__((address_space(1))) unsigned*)(Bt + (size_t)(n0+r)*K + k0 + ch*8),
        (__attribute__((address_space(3))) unsigned*)(lsB + (w*(BN/32)+i)*512),
        16, 0, 0);
    }
    __syncthreads();
    #pragma unroll
    for (int kk = 0; kk < 64; kk += 32) {
      const int cb = (kk >> 3) + lg;
      s16x8 af[MF], bfr[NF];
      #pragma unroll
      for (int i = 0; i < MF; i++) {
        const int row = wm*(BM/2) + i*16 + l15;
        af[i] = *(const s16x8*)&lsA[row*64 + ((cb ^ (row & 7)) << 3)];
      }
      #pragma unroll
      for (int j = 0; j < NF; j++) {
        const int row = wn*(BN/2) + j*16 + l15;
        bfr[j] = *(const s16x8*)&lsB[row*64 + ((cb ^ (row & 7)) << 3)];
      }
      #pragma unroll
      for (int i = 0; i < MF; i++)
        #pragma unroll
        for (int j = 0; j < NF; j++)
          acc[i][j] = __builtin_amdgcn_mfma_f32_16x16x32_bf16(af[i], bfr[j], acc[i][j], 0, 0, 0);
    }
  }
  #pragma unroll
  for (int j = 0; j < NF; j++) {
    const int col = n0 + wn*(BN/2) + j*16 + l15;
    const float bv = bias[col];
    #pragma unroll
    for (int i = 0; i < MF; i++) {
      #pragma unroll
      for (int r = 0; r < 4; r++) {
        const int row = m0 + wm*(BM/2) + i*16 + (lg << 2) + r;
        float v = acc[i][j][r] + bv;
        if (ACT == 1) v = gelu_f(v);
        if constexpr (OUT == 0 || OUT == 2) C32[(size_t)row*N + col] = v;
        if constexpr (OUT == 1 || OUT == 2) C16[(size_t)row*N + col] = f2b(v);
      }
    }
  }
}

// ---------------------------------------------------------------- attention
// Swapped QK^T: sc = mfma(K, Q) so lane owns q-row (l&15) with kv = mf*16+4*lg+r
// in registers -> in-register row softmax (2+2 shfl vs 32). Defer-max (THR=8).
// P -> per-wave LDS (no barrier needed), PV unchanged.
__global__ __launch_bounds__(256)
void attn_fwd(const u16* __restrict__ q, const u16* __restrict__ k,
              const u16* __restrict__ vt, u16* __restrict__ ctx, int qs)
{
  int bx = blockIdx.x, by = blockIdx.y;
  xcd_swz(gridDim.x, gridDim.y, bx, by);
  const int qt = bx, bh = by;
  const int b = bh / NHD, h = bh - b*NHD;
  __shared__ __align__(16) u16 lsK[64][72];
  __shared__ __align__(16) u16 lsV[64][72];
  __shared__ __align__(16) u16 lsP[4][16][72];
  const int t = threadIdx.x, lane = t & 63, w = t >> 6;
  const int l15 = lane & 15, lg = lane >> 4;

  const int qrow = qt*64 + w*16 + l15;
  const size_t qoff = (size_t)(b*SS + qrow)*qs + h*DHD;
  const s16x8 qf0 = *(const s16x8*)&q[qoff + (lg << 3)];
  const s16x8 qf1 = *(const s16x8*)&q[qoff + 32 + (lg << 3)];

  float m_run = -1e30f, l_run = 0.f;
  f32x4 oacc[4];
  #pragma unroll
  for (int j = 0; j < 4; j++) oacc[j] = (f32x4){0.f,0.f,0.f,0.f};

  const u16* kbase = k + (size_t)(b*SS)*qs + h*DHD;
  const u16* vbase = vt + (size_t)bh*DHD*SS;

  for (int kt = 0; kt < SS/64; kt++) {
    __syncthreads();
    for (int c = t; c < 512; c += 256) {
      int r = c >> 3, cc = (c & 7) << 3;
      *(s16x8*)&lsK[r][cc] = *(const s16x8*)&kbase[(size_t)(kt*64 + r)*qs + cc];
    }
    for (int c = t; c < 512; c += 256) {
      int r = c >> 3, cc = (c & 7) << 3;
      *(s16x8*)&lsV[r][cc] = *(const s16x8*)&vbase[(size_t)r*SS + kt*64 + cc];
    }
    __syncthreads();

    // QK^T swapped: D[kv][q]; lane: q = l15, kv = mf*16 + 4*lg + r
    f32x4 sc[4];
    #pragma unroll
    for (int mf = 0; mf < 4; mf++) sc[mf] = (f32x4){0.f,0.f,0.f,0.f};
    #pragma unroll
    for (int kk = 0; kk < 2; kk++) {
      const int ko = kk*32 + (lg << 3);
      const s16x8 qv = kk ? qf1 : qf0;        // B-frag: B[k][q] = Q[q][k]
      #pragma unroll
      for (int mf = 0; mf < 4; mf++) {
        s16x8 kf = *(const s16x8*)&lsK[mf*16 + l15][ko];   // A-frag: K rows
        sc[mf] = __builtin_amdgcn_mfma_f32_16x16x32_bf16(kf, qv, sc[mf], 0, 0, 0);
      }
    }
    // in-register row softmax
    float pmax = sc[0][0];
    #pragma unroll
    for (int mf = 0; mf < 4; mf++)
      #pragma unroll
      for (int r = 0; r < 4; r++) pmax = fmaxf(pmax, sc[mf][r]);
    pmax *= 0.125f;
    pmax = fmaxf(pmax, __shfl_xor(pmax, 16, 64));
    pmax = fmaxf(pmax, __shfl_xor(pmax, 32, 64));
    const bool need = !__all(pmax - m_run <= 8.0f);   // defer-max THR=8
    const float nm = need ? fmaxf(m_run, pmax) : m_run;
    float sum = 0.f;
    #pragma unroll
    for (int mf = 0; mf < 4; mf++) {
      u16x4 ph;
      #pragma unroll
      for (int r = 0; r < 4; r++) {
        const float p = __expf(sc[mf][r]*0.125f - nm);
        sum += p;
        ph[r] = f2b(p);
      }
      *(u16x4*)&lsP[w][l15][mf*16 + (lg << 2)] = ph;   // P[q][kv]
    }
    sum += __shfl_xor(sum, 16, 64);
    sum += __shfl_xor(sum, 32, 64);
    if (need) {                                        // wave-uniform branch
      const float alpha = __expf(m_run - nm);
      l_run = l_run*alpha + sum;
      m_run = nm;
      #pragma unroll
      for (int r = 0; r < 4; r++) {
        const float ar = __shfl(alpha, (lg << 2) + r, 64);
        #pragma unroll
        for (int j = 0; j < 4; j++) oacc[j][r] *= ar;
      }
    } else {
      l_run += sum;
    }
    // PV: lsP is per-wave (lgkmcnt orders write->read), lsV synced above
    #pragma unroll
    for (int ks = 0; ks < 2; ks++) {
      const int ko = ks*32 + (lg << 3);
      const s16x8 pf = *(const s16x8*)&lsP[w][l15][ko];
      #pragma unroll
      for (int j = 0; j < 4; j++) {
        s16x8 vf = *(const s16x8*)&lsV[j*16 + l15][ko];
        oacc[j] = __builtin_amdgcn_mfma_f32_16x16x32_bf16(pf, vf, oacc[j], 0, 0, 0);
      }
    }
  }
  const float linv = 1.f / l_run;                      // per q = l15
  #pragma unroll
  for (int r = 0; r < 4; r++) {
    const float lr = __shfl(linv, (lg << 2) + r, 64);
    #pragma unroll
    for (int j = 0; j < 4; j++) {
      const int row = qt*64 + w*16 + (lg << 2) + r;
      ctx[((size_t)(b*SS + row))*HH + h*DHD + j*16 + l15] = f2b(oacc[j][r] * lr);
    }
  }
}

// ---------------------------------------------------------------- adapter
__global__ __launch_bounds__(256)
void adp_gather(const float* __restrict__ d, const int* __restrict__ nidx,
                const int* __restrict__ eidx, float* __restrict__ esum,
                float* __restrict__ ecnt)
{
  const int gi = blockIdx.x*4 + (threadIdx.x >> 6);
  const int lane = threadIdx.x & 63;
  const int b = gi >> 12, i = gi & (EIC - 1);
  const int n = nidx[(size_t)b*EIC + i];
  const int e = eidx[(size_t)b*EIC + i];
  const float val = d[((size_t)b*SS + n)*RR + lane];
  atomicAdd(&esum[((size_t)b*NEC + e)*RR + lane], val);
  if (lane == 0) atomicAdd(&ecnt[(size_t)b*NEC + e], 1.0f);
}

__global__ __launch_bounds__(256)
void adp_edge(const float* __restrict__ esum, const float* __restrict__ ecnt,
              const int* __restrict__ types, const float* __restrict__ temb,
              float* __restrict__ e_out)
{
  const int ge = blockIdx.x*4 + (threadIdx.x >> 6);
  const int lane = threadIdx.x & 63;
  const int b = ge >> 9, e = ge & (NEC - 1);
  const float cnt = fmaxf(ecnt[(size_t)b*NEC + e], 1.0f);
  const int ty = types[(size_t)b*NEC + e];
  e_out[((size_t)b*NEC + e)*RR + lane] =
      esum[((size_t)b*NEC + e)*RR + lane]/cnt + temb[(size_t)ty*RR + lane];
}

__global__ __launch_bounds__(256)
void adp_scatter(const float* __restrict__ e_out, const int* __restrict__ nidx,
                 const int* __restrict__ eidx, float* __restrict__ nsum,
                 float* __restrict__ ncnt)
{
  const int gi = blockIdx.x*4 + (threadIdx.x >> 6);
  const int lane = threadIdx.x & 63;
  const int b = gi >> 12, i = gi & (EIC - 1);
  const int n = nidx[(size_t)b*EIC + i];
  const int e = eidx[(size_t)b*EIC + i];
  atomicAdd(&nsum[((size_t)b*SS + n)*RR + lane], e_out[((size_t)b*NEC + e)*RR + lane]);
  if (lane == 0) atomicAdd(&ncnt[(size_t)b*SS + n], 1.0f);
}

__global__ __launch_bounds__(256)
void adp_node(const float* __restrict__ nsum, const float* __restrict__ ncnt,
              u16* __restrict__ u)
{
  const int gn = blockIdx.x*4 + (threadIdx.x >> 6);
  const int lane = threadIdx.x & 63;
  const float cnt = fmaxf(ncnt[gn], 1.0f);
  u[(size_t)gn*RR + lane] = f2b(nsum[(size_t)gn*RR + lane]/cnt);
}

// ---------------------------------------------------------------- layernorm
__global__ __launch_bounds__(256)
void ln3(const float* __restrict__ a, const float* __restrict__ bb,
         const float* __restrict__ c, const float* __restrict__ g,
         const float* __restrict__ be, float* __restrict__ out,
         u16* __restrict__ outb)
{
  const int row = blockIdx.x, t = threadIdx.x;
  const size_t base = (size_t)row*HH;
  float v[3]; float s = 0.f, s2 = 0.f;
  #pragma unroll
  for (int i = 0; i < 3; i++) {
    int col = t + i*256;
    float x = a[base+col] + bb[base+col] + c[base+col];
    v[i] = x; s += x; s2 += x*x;
  }
  #pragma unroll
  for (int o = 1; o < 64; o <<= 1) { s += __shfl_xor(s, o, 64); s2 += __shfl_xor(s2, o, 64); }
  __shared__ float red[2][4];
  if ((t & 63) == 0) { red[0][t>>6] = s; red[1][t>>6] = s2; }
  __syncthreads();
  const float S  = red[0][0]+red[0][1]+red[0][2]+red[0][3];
  const float S2 = red[1][0]+red[1][1]+red[1][2]+red[1][3];
  const float mean = S*(1.0f/HH);
  const float var  = S2*(1.0f/HH) - mean*mean;
  const float inv  = rsqrtf(var + 1e-5f);
  #pragma unroll
  for (int i = 0; i < 3; i++) {
    int col = t + i*256;
    const float res = (v[i]-mean)*inv*g[col] + be[col];
    out[base+col] = res;
    if (outb) outb[base+col] = f2b(res);
  }
}

// ---------------------------------------------------------------- host
extern "C" void kernel_launch(void* const* d_in, const int* in_sizes, int n_in,
                              void* d_out, int out_size, void* d_ws, size_t ws_size,
                              hipStream_t stream)
{
  (void)in_sizes; (void)n_in; (void)out_size; (void)ws_size;
  const float* x        = (const float*)d_in[0];
  const int* node_idx   = (const int*)d_in[1];
  const int* edge_idx   = (const int*)d_in[2];
  const int* edge_types = (const int*)d_in[3];
  const float* Wq = (const float*)d_in[4];  const float* bq = (const float*)d_in[5];
  const float* Wk = (const float*)d_in[6];  const float* bk = (const float*)d_in[7];
  const float* Wv = (const float*)d_in[8];  const float* bv = (const float*)d_in[9];
  const float* Wo = (const float*)d_in[10]; const float* bo = (const float*)d_in[11];
  const float* ln1_g = (const float*)d_in[12]; const float* ln1_b = (const float*)d_in[13];
  const float* a1_dw = (const float*)d_in[14]; const float* a1_db = (const float*)d_in[15];
  const float* a1_uw = (const float*)d_in[16]; const float* a1_ub = (const float*)d_in[17];
  const float* a1_temb = (const float*)d_in[18];
  const float* Wi  = (const float*)d_in[19]; const float* bi  = (const float*)d_in[20];
  const float* Wd2 = (const float*)d_in[21]; const float* bd2 = (const float*)d_in[22];
  const float* ln2_g = (const float*)d_in[23]; const float* ln2_b = (const float*)d_in[24];
  const float* a2_dw = (const float*)d_in[25]; const float* a2_db = (const float*)d_in[26];
  const float* a2_uw = (const float*)d_in[27]; const float* a2_ub = (const float*)d_in[28];
  const float* a2_temb = (const float*)d_in[29];

  char* ws = (char*)d_ws;
  size_t off = 0;
  auto take = [&](size_t bytes) -> size_t {
    size_t o = off; off += (bytes + 255) & ~(size_t)255; return o;
  };
  const size_t actB2 = (size_t)8192*768*2;
  const size_t actB4 = (size_t)8192*768*4;
  const size_t oWqkvT = take(2304ull*768*2);
  const size_t oWoT   = take(768ull*768*2);
  const size_t oWiT   = take(768ull*3072*2);
  const size_t oWd2T  = take(768ull*3072*2);
  const size_t oA1dwT = take(768ull*64*2);
  const size_t oA1uwT = take(768ull*64*2);
  const size_t oA2dwT = take(768ull*64*2);
  const size_t oA2uwT = take(768ull*64*2);
  const size_t oBqkv  = take(2304ull*4);
  const size_t oXbf  = take(actB2);
  const size_t oQkv  = take((size_t)8192*2304*2);
  const size_t oVt   = take(actB2);
  const size_t oCtx  = take(actB2);
  const size_t oAD   = take(actB4);
  const size_t oAdp  = take(actB4);
  const size_t oAO   = take(actB4);
  const size_t oAOb  = take(actB2);
  const size_t oDb   = take((size_t)8192*64*4);
  const size_t oUb   = take((size_t)8192*64*2);
  const size_t oEsum = take((size_t)8*512*64*4);
  const size_t oEcnt = take((size_t)8*512*4);
  const size_t oNsum = take((size_t)8*1024*64*4);
  const size_t oNcnt = take((size_t)8*1024*4);
  const size_t oEbuf = take((size_t)8*512*64*4);
  const size_t oInter = oQkv;
  const size_t oFF    = oAD;
  const size_t oFFb   = oCtx;
  const size_t oADb   = oXbf;
  const size_t zeroBytes = oEbuf - oEsum;

  u16* WqkvT = (u16*)(ws+oWqkvT); u16* WoT = (u16*)(ws+oWoT);
  u16* WiT = (u16*)(ws+oWiT);     u16* Wd2T = (u16*)(ws+oWd2T);
  u16* A1dwT = (u16*)(ws+oA1dwT); u16* A1uwT = (u16*)(ws+oA1uwT);
  u16* A2dwT = (u16*)(ws+oA2dwT); u16* A2uwT = (u16*)(ws+oA2uwT);
  float* bias_qkv = (float*)(ws+oBqkv);
  u16* xbf = (u16*)(ws+oXbf);
  u16* qkv = (u16*)(ws+oQkv);
  u16* vtb = (u16*)(ws+oVt);  u16* ctx = (u16*)(ws+oCtx);
  float* attn_dense = (float*)(ws+oAD); u16* attn_dense_bf = (u16*)(ws+oADb);
  float* adb = (float*)(ws+oAdp);
  float* attn_out = (float*)(ws+oAO);   u16* attn_out_bf = (u16*)(ws+oAOb);
  float* dbuf = (float*)(ws+oDb);       u16* ubuf = (u16*)(ws+oUb);
  float* esum = (float*)(ws+oEsum); float* ecnt = (float*)(ws+oEcnt);
  float* nsum = (float*)(ws+oNsum); float* ncnt = (float*)(ws+oNcnt);
  float* ebuf = (float*)(ws+oEbuf);
  u16* inter = (u16*)(ws+oInter);
  float* ffb = (float*)(ws+oFF);  u16* ffb_bf = (u16*)(ws+oFFb);

  const dim3 blk(256);
  wtrans<<<dim3(12,12), blk, 0, stream>>>(Wq,  WqkvT,            768, 768);
  wtrans<<<dim3(12,12), blk, 0, stream>>>(Wk,  WqkvT + 768*768,  768, 768);
  wtrans<<<dim3(12,12), blk, 0, stream>>>(Wv,  WqkvT + 2*768*768,768, 768);
  wtrans<<<dim3(12,12), blk, 0, stream>>>(Wo,  WoT,  768, 768);
  wtrans<<<dim3(12,48), blk, 0, stream>>>(Wi,  WiT,  768, 3072);
  wtrans<<<dim3(48,12), blk, 0, stream>>>(Wd2, Wd2T, 3072, 768);
  wtrans<<<dim3(12,1),  blk, 0, stream>>>(a1_dw, A1dwT, 768, 64);
  wtrans<<<dim3(1,12),  blk, 0, stream>>>(a1_uw, A1uwT, 64, 768);
  wtrans<<<dim3(12,1),  blk, 0, stream>>>(a2_dw, A2dwT, 768, 64);
  wtrans<<<dim3(1,12),  blk, 0, stream>>>(a2_uw, A2uwT, 64, 768);
  hipMemcpyAsync(bias_qkv,        bq, 768*4, hipMemcpyDeviceToDevice, stream);
  hipMemcpyAsync(bias_qkv + 768,  bk, 768*4, hipMemcpyDeviceToDevice, stream);
  hipMemcpyAsync(bias_qkv + 1536, bv, 768*4, hipMemcpyDeviceToDevice, stream);
  cvt16<<<3072, blk, 0, stream>>>(x, xbf);
  // fused QKV
  gemm_bt<64,128,0,1><<<dim3(18,128), blk, 0, stream>>>(xbf, WqkvT, bias_qkv, nullptr, qkv, 8192, 2304, 768);
  vtrans<<<dim3(16,96), blk, 0, stream>>>(qkv + 1536, vtb, 2304);
  attn_fwd<<<dim3(16,96), blk, 0, stream>>>(qkv, qkv + 768, vtb, ctx, 2304);
  gemm_bt<64,128,0,2><<<dim3(6,128), blk, 0, stream>>>(ctx, WoT, bo, attn_dense, attn_dense_bf, 8192, 768, 768);
  // adapter 1
  gemm_bt<64,64,1,0><<<dim3(1,128), blk, 0, stream>>>(attn_dense_bf, A1dwT, a1_db, dbuf, nullptr, 8192, 64, 768);
  hipMemsetAsync(ws + oEsum, 0, zeroBytes, stream);
  adp_gather<<<8192, blk, 0, stream>>>(dbuf, node_idx, edge_idx, esum, ecnt);
  adp_edge<<<1024, blk, 0, stream>>>(esum, ecnt, edge_types, a1_temb, ebuf);
  adp_scatter<<<8192, blk, 0, stream>>>(ebuf, node_idx, edge_idx, nsum, ncnt);
  adp_node<<<2048, blk, 0, stream>>>(nsum, ncnt, ubuf);
  gemm_bt<64,128,0,0><<<dim3(6,128), blk, 0, stream>>>(ubuf, A1uwT, a1_ub, adb, nullptr, 8192, 768, 64);
  ln3<<<8192, blk, 0, stream>>>(attn_dense, adb, x, ln1_g, ln1_b, attn_out, attn_out_bf);
  // FFN
  gemm_bt<64,128,1,1><<<dim3(24,128), blk, 0, stream>>>(attn_out_bf, WiT, bi, nullptr, inter, 8192, 3072, 768);
  gemm_bt<64,128,0,2><<<dim3(6,128), blk, 0, stream>>>(inter, Wd2T, bd2, ffb, ffb_bf, 8192, 768, 3072);
  // adapter 2
  gemm_bt<64,64,1,0><<<dim3(1,128), blk, 0, stream>>>(ffb_bf, A2dwT, a2_db, dbuf, nullptr, 8192, 64, 768);
  hipMemsetAsync(ws + oEsum, 0, zeroBytes, stream);
  adp_gather<<<8192, blk, 0, stream>>>(dbuf, node_idx, edge_idx, esum, ecnt);
  adp_edge<<<1024, blk, 0, stream>>>(esum, ecnt, edge_types, a2_temb, ebuf);
  adp_scatter<<<8192, blk, 0, stream>>>(ebuf, node_idx, edge_idx, nsum, ncnt);
  adp_node<<<2048, blk, 0, stream>>>(nsum, ncnt, ubuf);
  gemm_bt<64,128,0,0><<<dim3(6,128), blk, 0, stream>>>(ubuf, A2uwT, a2_ub, adb, nullptr, 8192, 768, 64);
  ln3<<<8192, blk, 0, stream>>>(ffb, adb, attn_out, ln2_g, ln2_b, (float*)d_out, nullptr);
}

// Round 12
// 568.964 us; speedup vs baseline: 1.8460x; 1.0265x over previous
//
#include <hip/hip_runtime.h>

typedef unsigned short u16;
typedef __attribute__((ext_vector_type(8))) short s16x8;
typedef __attribute__((ext_vector_type(4))) float f32x4;
typedef __attribute__((ext_vector_type(4))) unsigned short u16x4;

#define NB 8
#define SS 1024
#define HH 768
#define NHD 12
#define DHD 64
#define FFD 3072
#define RR 64
#define NEC 512
#define EIC 4096

__device__ __forceinline__ float b2f(u16 u){ return __uint_as_float(((unsigned)u)<<16); }
__device__ __forceinline__ u16 f2b(float f){
  unsigned x = __float_as_uint(f);
  return (u16)((x + 0x7fffu + ((x>>16)&1u)) >> 16);   // RNE
}
__device__ __forceinline__ float gelu_f(float x){
  return 0.5f*x*(1.0f + tanhf(0.79788456080286535588f*(x + 0.044715f*x*x*x)));
}
// bijective XCD-chunked swizzle (m204)
__device__ __forceinline__ void xcd_swz(int gx, int gy, int& bx, int& by){
  const int nwg = gx*gy;
  const int flat = by*gx + bx;
  const int qch = nwg >> 3, rch = nwg & 7;
  const int xcd = flat & 7, idx = flat >> 3;
  const int swz = (xcd < rch ? xcd*(qch+1) : rch*(qch+1) + (xcd-rch)*qch) + idx;
  bx = swz % gx; by = swz / gx;
}

// ---------------------------------------------------------------- fp32->bf16
__global__ __launch_bounds__(256)
void cvt16(const float* __restrict__ src, u16* __restrict__ dst)
{
  const size_t i = ((size_t)blockIdx.x*256 + threadIdx.x)*8;
  float4 a = *(const float4*)&src[i];
  float4 b = *(const float4*)&src[i+4];
  u16x4 h1; h1.x=f2b(a.x); h1.y=f2b(a.y); h1.z=f2b(a.z); h1.w=f2b(a.w);
  u16x4 h2; h2.x=f2b(b.x); h2.y=f2b(b.y); h2.z=f2b(b.z); h2.w=f2b(b.w);
  *(u16x4*)&dst[i] = h1; *(u16x4*)&dst[i+4] = h2;
}

// ---------------------------------------------------------------- transpose
__global__ __launch_bounds__(256)
void wtrans(const float* __restrict__ src, u16* __restrict__ dst, int R, int C)
{
  __shared__ u16 tile[64][68];
  const int r0 = blockIdx.x*64, c0 = blockIdx.y*64;
  const int t = threadIdx.x;
  const int tr = t >> 4, tc = (t & 15) * 4;
  for (int i = 0; i < 4; i++) {
    int r = tr + i*16;
    float4 v4 = *(const float4*)&src[(size_t)(r0+r)*C + c0 + tc];
    u16x4 h; h.x = f2b(v4.x); h.y = f2b(v4.y); h.z = f2b(v4.z); h.w = f2b(v4.w);
    *(u16x4*)&tile[r][tc] = h;
  }
  __syncthreads();
  for (int i = 0; i < 4; i++) {
    int rr = tr + i*16;
    u16x4 v;
    v.x = tile[tc+0][rr]; v.y = tile[tc+1][rr];
    v.z = tile[tc+2][rr]; v.w = tile[tc+3][rr];
    *(u16x4*)&dst[(size_t)(c0+rr)*R + r0 + tc] = v;
  }
}

// V (bf16, row stride vs) -> Vt [B*NH][DH][S]. grid (S/64, B*NH), block 256.
__global__ __launch_bounds__(256)
void vtrans(const u16* __restrict__ v, u16* __restrict__ vt, int vs)
{
  __shared__ u16 tile[64][68];
  const int st = blockIdx.x, bh = blockIdx.y;
  const int b = bh / NHD, h = bh - b*NHD;
  const u16* src = v + (size_t)(b*SS + st*64)*vs + h*DHD;
  u16* dst = vt + (size_t)bh*DHD*SS + st*64;
  const int t = threadIdx.x;
  const int tr = t >> 4, tc = (t & 15) * 4;
  for (int i = 0; i < 4; i++) {
    int r = tr + i*16;
    *(u16x4*)&tile[r][tc] = *(const u16x4*)&src[(size_t)r*vs + tc];
  }
  __syncthreads();
  for (int i = 0; i < 4; i++) {
    int rr = tr + i*16;
    u16x4 vv;
    vv.x = tile[tc+0][rr]; vv.y = tile[tc+1][rr];
    vv.z = tile[tc+2][rr]; vv.w = tile[tc+3][rr];
    *(u16x4*)&dst[(size_t)rr*SS + tc] = vv;
  }
}

// ---------------------------------------------------------------- GEMM
// Staging: global_load_lds 16B/lane, linear LDS dest, both-sides chunk XOR.
template<int BM, int BN, int ACT, int OUT>
__global__ __launch_bounds__(256)
void gemm_bt(const u16* __restrict__ A, const u16* __restrict__ Bt,
             const float* __restrict__ bias, float* __restrict__ C32,
             u16* __restrict__ C16, int M, int N, int K)
{
  constexpr int MF = BM/32;
  constexpr int NF = BN/32;
  __shared__ __align__(16) u16 lsA[BM*64];
  __shared__ __align__(16) u16 lsB[BN*64];
  int bx = blockIdx.x, by = blockIdx.y;
  xcd_swz(gridDim.x, gridDim.y, bx, by);
  const int m0 = by*BM, n0 = bx*BN;
  const int t = threadIdx.x, lane = t & 63, w = t >> 6;
  const int wm = w >> 1, wn = w & 1;
  const int l15 = lane & 15, lg = lane >> 4;

  f32x4 acc[MF][NF];
  #pragma unroll
  for (int i = 0; i < MF; i++)
    #pragma unroll
    for (int j = 0; j < NF; j++) acc[i][j] = (f32x4){0.f,0.f,0.f,0.f};

  for (int k0 = 0; k0 < K; k0 += 64) {
    __syncthreads();
    #pragma unroll
    for (int i = 0; i < BM/32; i++) {
      const int p = (w*(BM/32) + i)*64 + lane;
      const int r = p >> 3;
      const int ch = (p & 7) ^ (r & 7);
      __builtin_amdgcn_global_load_lds(
        (const __attribute__((address_space(1))) unsigned*)(A + (size_t)(m0+r)*K + k0 + ch*8),
        (__attribute__((address_space(3))) unsigned*)(lsA + (w*(BM/32)+i)*512),
        16, 0, 0);
    }
    #pragma unroll
    for (int i = 0; i < BN/32; i++) {
      const int p = (w*(BN/32) + i)*64 + lane;
      const int r = p >> 3;
      const int ch = (p & 7) ^ (r & 7);
      __builtin_amdgcn_global_load_lds(
        (const __attribute__((address_space(1))) unsigned*)(Bt + (size_t)(n0+r)*K + k0 + ch*8),
        (__attribute__((address_space(3))) unsigned*)(lsB + (w*(BN/32)+i)*512),
        16, 0, 0);
    }
    __syncthreads();
    #pragma unroll
    for (int kk = 0; kk < 64; kk += 32) {
      const int cb = (kk >> 3) + lg;
      s16x8 af[MF], bfr[NF];
      #pragma unroll
      for (int i = 0; i < MF; i++) {
        const int row = wm*(BM/2) + i*16 + l15;
        af[i] = *(const s16x8*)&lsA[row*64 + ((cb ^ (row & 7)) << 3)];
      }
      #pragma unroll
      for (int j = 0; j < NF; j++) {
        const int row = wn*(BN/2) + j*16 + l15;
        bfr[j] = *(const s16x8*)&lsB[row*64 + ((cb ^ (row & 7)) << 3)];
      }
      #pragma unroll
      for (int i = 0; i < MF; i++)
        #pragma unroll
        for (int j = 0; j < NF; j++)
          acc[i][j] = __builtin_amdgcn_mfma_f32_16x16x32_bf16(af[i], bfr[j], acc[i][j], 0, 0, 0);
    }
  }
  #pragma unroll
  for (int j = 0; j < NF; j++) {
    const int col = n0 + wn*(BN/2) + j*16 + l15;
    const float bv = bias[col];
    #pragma unroll
    for (int i = 0; i < MF; i++) {
      #pragma unroll
      for (int r = 0; r < 4; r++) {
        const int row = m0 + wm*(BM/2) + i*16 + (lg << 2) + r;
        float v = acc[i][j][r] + bv;
        if (ACT == 1) v = gelu_f(v);
        if constexpr (OUT == 0 || OUT == 2) C32[(size_t)row*N + col] = v;
        if constexpr (OUT == 1 || OUT == 2) C16[(size_t)row*N + col] = f2b(v);
      }
    }
  }
}

// ---------------------------------------------------------------- attention
// Swapped QK^T + in-register softmax + defer-max (THR=8).
// K/V staged via global_load_lds (linear dest, both-sides chunk XOR);
// P packed via v_cvt_pk_bf16_f32 (RNE, 2 instr / 4 vals).
__global__ __launch_bounds__(256)
void attn_fwd(const u16* __restrict__ q, const u16* __restrict__ k,
              const u16* __restrict__ vt, u16* __restrict__ ctx, int qs)
{
  int bx = blockIdx.x, by = blockIdx.y;
  xcd_swz(gridDim.x, gridDim.y, bx, by);
  const int qt = bx, bh = by;
  const int b = bh / NHD, h = bh - b*NHD;
  __shared__ __align__(16) u16 lsK[64*64];
  __shared__ __align__(16) u16 lsV[64*64];
  __shared__ __align__(16) u16 lsP[4][16][72];
  const int t = threadIdx.x, lane = t & 63, w = t >> 6;
  const int l15 = lane & 15, lg = lane >> 4;

  const int qrow = qt*64 + w*16 + l15;
  const size_t qoff = (size_t)(b*SS + qrow)*qs + h*DHD;
  const s16x8 qf0 = *(const s16x8*)&q[qoff + (lg << 3)];
  const s16x8 qf1 = *(const s16x8*)&q[qoff + 32 + (lg << 3)];

  float m_run = -1e30f, l_run = 0.f;
  f32x4 oacc[4];
  #pragma unroll
  for (int j = 0; j < 4; j++) oacc[j] = (f32x4){0.f,0.f,0.f,0.f};

  const u16* kbase = k + (size_t)(b*SS)*qs + h*DHD;
  const u16* vbase = vt + (size_t)bh*DHD*SS;

  for (int kt = 0; kt < SS/64; kt++) {
    __syncthreads();
    #pragma unroll
    for (int i = 0; i < 2; i++) {
      const int p = (w*2 + i)*64 + lane;
      const int r = p >> 3;
      const int ch = (p & 7) ^ (r & 7);
      __builtin_amdgcn_global_load_lds(
        (const __attribute__((address_space(1))) unsigned*)(kbase + (size_t)(kt*64 + r)*qs + ch*8),
        (__attribute__((address_space(3))) unsigned*)(lsK + (w*2+i)*512), 16, 0, 0);
      __builtin_amdgcn_global_load_lds(
        (const __attribute__((address_space(1))) unsigned*)(vbase + (size_t)r*SS + kt*64 + ch*8),
        (__attribute__((address_space(3))) unsigned*)(lsV + (w*2+i)*512), 16, 0, 0);
    }
    __syncthreads();

    // QK^T swapped: D[kv][q]; lane: q = l15, kv = mf*16 + 4*lg + r
    f32x4 sc[4];
    #pragma unroll
    for (int mf = 0; mf < 4; mf++) sc[mf] = (f32x4){0.f,0.f,0.f,0.f};
    #pragma unroll
    for (int kk = 0; kk < 2; kk++) {
      const int cb = kk*4 + lg;
      const s16x8 qv = kk ? qf1 : qf0;
      #pragma unroll
      for (int mf = 0; mf < 4; mf++) {
        const int row = mf*16 + l15;
        s16x8 kf = *(const s16x8*)&lsK[row*64 + ((cb ^ (row & 7)) << 3)];
        sc[mf] = __builtin_amdgcn_mfma_f32_16x16x32_bf16(kf, qv, sc[mf], 0, 0, 0);
      }
    }
    // in-register row softmax
    float pmax = sc[0][0];
    #pragma unroll
    for (int mf = 0; mf < 4; mf++)
      #pragma unroll
      for (int r = 0; r < 4; r++) pmax = fmaxf(pmax, sc[mf][r]);
    pmax *= 0.125f;
    pmax = fmaxf(pmax, __shfl_xor(pmax, 16, 64));
    pmax = fmaxf(pmax, __shfl_xor(pmax, 32, 64));
    const bool need = !__all(pmax - m_run <= 8.0f);   // defer-max THR=8
    const float nm = need ? fmaxf(m_run, pmax) : m_run;
    const float c1 = 0.125f * 1.44269504088896f;      // to exp2 domain
    const float c2 = -nm * 1.44269504088896f;
    float sum = 0.f;
    #pragma unroll
    for (int mf = 0; mf < 4; mf++) {
      float p0 = exp2f(fmaf(sc[mf][0], c1, c2));
      float p1 = exp2f(fmaf(sc[mf][1], c1, c2));
      float p2 = exp2f(fmaf(sc[mf][2], c1, c2));
      float p3 = exp2f(fmaf(sc[mf][3], c1, c2));
      sum += (p0 + p1) + (p2 + p3);
      unsigned r01, r23;
      asm("v_cvt_pk_bf16_f32 %0, %1, %2" : "=v"(r01) : "v"(p0), "v"(p1));
      asm("v_cvt_pk_bf16_f32 %0, %1, %2" : "=v"(r23) : "v"(p2), "v"(p3));
      uint2 pk; pk.x = r01; pk.y = r23;
      *(uint2*)&lsP[w][l15][mf*16 + (lg << 2)] = pk;   // P[q][kv]
    }
    sum += __shfl_xor(sum, 16, 64);
    sum += __shfl_xor(sum, 32, 64);
    if (need) {                                        // wave-uniform branch
      const float alpha = __expf(m_run - nm);
      l_run = l_run*alpha + sum;
      m_run = nm;
      #pragma unroll
      for (int r = 0; r < 4; r++) {
        const float ar = __shfl(alpha, (lg << 2) + r, 64);
        #pragma unroll
        for (int j = 0; j < 4; j++) oacc[j][r] *= ar;
      }
    } else {
      l_run += sum;
    }
    // PV: lsP per-wave (lgkmcnt orders write->read), lsV synced above
    #pragma unroll
    for (int ks = 0; ks < 2; ks++) {
      const int cb = ks*4 + lg;
      const s16x8 pf = *(const s16x8*)&lsP[w][l15][ks*32 + (lg << 3)];
      #pragma unroll
      for (int j = 0; j < 4; j++) {
        const int row = j*16 + l15;
        s16x8 vf = *(const s16x8*)&lsV[row*64 + ((cb ^ (row & 7)) << 3)];
        oacc[j] = __builtin_amdgcn_mfma_f32_16x16x32_bf16(pf, vf, oacc[j], 0, 0, 0);
      }
    }
  }
  const float linv = 1.f / l_run;                      // per q = l15
  #pragma unroll
  for (int r = 0; r < 4; r++) {
    const float lr = __shfl(linv, (lg << 2) + r, 64);
    #pragma unroll
    for (int j = 0; j < 4; j++) {
      const int row = qt*64 + w*16 + (lg << 2) + r;
      ctx[((size_t)(b*SS + row))*HH + h*DHD + j*16 + l15] = f2b(oacc[j][r] * lr);
    }
  }
}

// ---------------------------------------------------------------- adapter
__global__ __launch_bounds__(256)
void adp_gather(const float* __restrict__ d, const int* __restrict__ nidx,
                const int* __restrict__ eidx, float* __restrict__ esum,
                float* __restrict__ ecnt)
{
  const int gi = blockIdx.x*4 + (threadIdx.x >> 6);
  const int lane = threadIdx.x & 63;
  const int b = gi >> 12, i = gi & (EIC - 1);
  const int n = nidx[(size_t)b*EIC + i];
  const int e = eidx[(size_t)b*EIC + i];
  const float val = d[((size_t)b*SS + n)*RR + lane];
  atomicAdd(&esum[((size_t)b*NEC + e)*RR + lane], val);
  if (lane == 0) atomicAdd(&ecnt[(size_t)b*NEC + e], 1.0f);
}

__global__ __launch_bounds__(256)
void adp_edge(const float* __restrict__ esum, const float* __restrict__ ecnt,
              const int* __restrict__ types, const float* __restrict__ temb,
              float* __restrict__ e_out)
{
  const int ge = blockIdx.x*4 + (threadIdx.x >> 6);
  const int lane = threadIdx.x & 63;
  const int b = ge >> 9, e = ge & (NEC - 1);
  const float cnt = fmaxf(ecnt[(size_t)b*NEC + e], 1.0f);
  const int ty = types[(size_t)b*NEC + e];
  e_out[((size_t)b*NEC + e)*RR + lane] =
      esum[((size_t)b*NEC + e)*RR + lane]/cnt + temb[(size_t)ty*RR + lane];
}

__global__ __launch_bounds__(256)
void adp_scatter(const float* __restrict__ e_out, const int* __restrict__ nidx,
                 const int* __restrict__ eidx, float* __restrict__ nsum,
                 float* __restrict__ ncnt)
{
  const int gi = blockIdx.x*4 + (threadIdx.x >> 6);
  const int lane = threadIdx.x & 63;
  const int b = gi >> 12, i = gi & (EIC - 1);
  const int n = nidx[(size_t)b*EIC + i];
  const int e = eidx[(size_t)b*EIC + i];
  atomicAdd(&nsum[((size_t)b*SS + n)*RR + lane], e_out[((size_t)b*NEC + e)*RR + lane]);
  if (lane == 0) atomicAdd(&ncnt[(size_t)b*SS + n], 1.0f);
}

__global__ __launch_bounds__(256)
void adp_node(const float* __restrict__ nsum, const float* __restrict__ ncnt,
              u16* __restrict__ u)
{
  const int gn = blockIdx.x*4 + (threadIdx.x >> 6);
  const int lane = threadIdx.x & 63;
  const float cnt = fmaxf(ncnt[gn], 1.0f);
  u[(size_t)gn*RR + lane] = f2b(nsum[(size_t)gn*RR + lane]/cnt);
}

// ---------------------------------------------------------------- layernorm
__global__ __launch_bounds__(256)
void ln3(const float* __restrict__ a, const float* __restrict__ bb,
         const float* __restrict__ c, const float* __restrict__ g,
         const float* __restrict__ be, float* __restrict__ out,
         u16* __restrict__ outb)
{
  const int row = blockIdx.x, t = threadIdx.x;
  const size_t base = (size_t)row*HH;
  float v[3]; float s = 0.f, s2 = 0.f;
  #pragma unroll
  for (int i = 0; i < 3; i++) {
    int col = t + i*256;
    float x = a[base+col] + bb[base+col] + c[base+col];
    v[i] = x; s += x; s2 += x*x;
  }
  #pragma unroll
  for (int o = 1; o < 64; o <<= 1) { s += __shfl_xor(s, o, 64); s2 += __shfl_xor(s2, o, 64); }
  __shared__ float red[2][4];
  if ((t & 63) == 0) { red[0][t>>6] = s; red[1][t>>6] = s2; }
  __syncthreads();
  const float S  = red[0][0]+red[0][1]+red[0][2]+red[0][3];
  const float S2 = red[1][0]+red[1][1]+red[1][2]+red[1][3];
  const float mean = S*(1.0f/HH);
  const float var  = S2*(1.0f/HH) - mean*mean;
  const float inv  = rsqrtf(var + 1e-5f);
  #pragma unroll
  for (int i = 0; i < 3; i++) {
    int col = t + i*256;
    const float res = (v[i]-mean)*inv*g[col] + be[col];
    out[base+col] = res;
    if (outb) outb[base+col] = f2b(res);
  }
}

// ---------------------------------------------------------------- host
extern "C" void kernel_launch(void* const* d_in, const int* in_sizes, int n_in,
                              void* d_out, int out_size, void* d_ws, size_t ws_size,
                              hipStream_t stream)
{
  (void)in_sizes; (void)n_in; (void)out_size; (void)ws_size;
  const float* x        = (const float*)d_in[0];
  const int* node_idx   = (const int*)d_in[1];
  const int* edge_idx   = (const int*)d_in[2];
  const int* edge_types = (const int*)d_in[3];
  const float* Wq = (const float*)d_in[4];  const float* bq = (const float*)d_in[5];
  const float* Wk = (const float*)d_in[6];  const float* bk = (const float*)d_in[7];
  const float* Wv = (const float*)d_in[8];  const float* bv = (const float*)d_in[9];
  const float* Wo = (const float*)d_in[10]; const float* bo = (const float*)d_in[11];
  const float* ln1_g = (const float*)d_in[12]; const float* ln1_b = (const float*)d_in[13];
  const float* a1_dw = (const float*)d_in[14]; const float* a1_db = (const float*)d_in[15];
  const float* a1_uw = (const float*)d_in[16]; const float* a1_ub = (const float*)d_in[17];
  const float* a1_temb = (const float*)d_in[18];
  const float* Wi  = (const float*)d_in[19]; const float* bi  = (const float*)d_in[20];
  const float* Wd2 = (const float*)d_in[21]; const float* bd2 = (const float*)d_in[22];
  const float* ln2_g = (const float*)d_in[23]; const float* ln2_b = (const float*)d_in[24];
  const float* a2_dw = (const float*)d_in[25]; const float* a2_db = (const float*)d_in[26];
  const float* a2_uw = (const float*)d_in[27]; const float* a2_ub = (const float*)d_in[28];
  const float* a2_temb = (const float*)d_in[29];

  char* ws = (char*)d_ws;
  size_t off = 0;
  auto take = [&](size_t bytes) -> size_t {
    size_t o = off; off += (bytes + 255) & ~(size_t)255; return o;
  };
  const size_t actB2 = (size_t)8192*768*2;
  const size_t actB4 = (size_t)8192*768*4;
  const size_t oWqkvT = take(2304ull*768*2);
  const size_t oWoT   = take(768ull*768*2);
  const size_t oWiT   = take(768ull*3072*2);
  const size_t oWd2T  = take(768ull*3072*2);
  const size_t oA1dwT = take(768ull*64*2);
  const size_t oA1uwT = take(768ull*64*2);
  const size_t oA2dwT = take(768ull*64*2);
  const size_t oA2uwT = take(768ull*64*2);
  const size_t oBqkv  = take(2304ull*4);
  const size_t oXbf  = take(actB2);
  const size_t oQkv  = take((size_t)8192*2304*2);
  const size_t oVt   = take(actB2);
  const size_t oCtx  = take(actB2);
  const size_t oAD   = take(actB4);
  const size_t oAdp  = take(actB4);
  const size_t oAO   = take(actB4);
  const size_t oAOb  = take(actB2);
  const size_t oDb   = take((size_t)8192*64*4);
  const size_t oUb   = take((size_t)8192*64*2);
  const size_t oEsum = take((size_t)8*512*64*4);
  const size_t oEcnt = take((size_t)8*512*4);
  const size_t oNsum = take((size_t)8*1024*64*4);
  const size_t oNcnt = take((size_t)8*1024*4);
  const size_t oEbuf = take((size_t)8*512*64*4);
  const size_t oInter = oQkv;
  const size_t oFF    = oAD;
  const size_t oFFb   = oCtx;
  const size_t oADb   = oXbf;
  const size_t zeroBytes = oEbuf - oEsum;

  u16* WqkvT = (u16*)(ws+oWqkvT); u16* WoT = (u16*)(ws+oWoT);
  u16* WiT = (u16*)(ws+oWiT);     u16* Wd2T = (u16*)(ws+oWd2T);
  u16* A1dwT = (u16*)(ws+oA1dwT); u16* A1uwT = (u16*)(ws+oA1uwT);
  u16* A2dwT = (u16*)(ws+oA2dwT); u16* A2uwT = (u16*)(ws+oA2uwT);
  float* bias_qkv = (float*)(ws+oBqkv);
  u16* xbf = (u16*)(ws+oXbf);
  u16* qkv = (u16*)(ws+oQkv);
  u16* vtb = (u16*)(ws+oVt);  u16* ctx = (u16*)(ws+oCtx);
  float* attn_dense = (float*)(ws+oAD); u16* attn_dense_bf = (u16*)(ws+oADb);
  float* adb = (float*)(ws+oAdp);
  float* attn_out = (float*)(ws+oAO);   u16* attn_out_bf = (u16*)(ws+oAOb);
  float* dbuf = (float*)(ws+oDb);       u16* ubuf = (u16*)(ws+oUb);
  float* esum = (float*)(ws+oEsum); float* ecnt = (float*)(ws+oEcnt);
  float* nsum = (float*)(ws+oNsum); float* ncnt = (float*)(ws+oNcnt);
  float* ebuf = (float*)(ws+oEbuf);
  u16* inter = (u16*)(ws+oInter);
  float* ffb = (float*)(ws+oFF);  u16* ffb_bf = (u16*)(ws+oFFb);

  const dim3 blk(256);
  wtrans<<<dim3(12,12), blk, 0, stream>>>(Wq,  WqkvT,            768, 768);
  wtrans<<<dim3(12,12), blk, 0, stream>>>(Wk,  WqkvT + 768*768,  768, 768);
  wtrans<<<dim3(12,12), blk, 0, stream>>>(Wv,  WqkvT + 2*768*768,768, 768);
  wtrans<<<dim3(12,12), blk, 0, stream>>>(Wo,  WoT,  768, 768);
  wtrans<<<dim3(12,48), blk, 0, stream>>>(Wi,  WiT,  768, 3072);
  wtrans<<<dim3(48,12), blk, 0, stream>>>(Wd2, Wd2T, 3072, 768);
  wtrans<<<dim3(12,1),  blk, 0, stream>>>(a1_dw, A1dwT, 768, 64);
  wtrans<<<dim3(1,12),  blk, 0, stream>>>(a1_uw, A1uwT, 64, 768);
  wtrans<<<dim3(12,1),  blk, 0, stream>>>(a2_dw, A2dwT, 768, 64);
  wtrans<<<dim3(1,12),  blk, 0, stream>>>(a2_uw, A2uwT, 64, 768);
  hipMemcpyAsync(bias_qkv,        bq, 768*4, hipMemcpyDeviceToDevice, stream);
  hipMemcpyAsync(bias_qkv + 768,  bk, 768*4, hipMemcpyDeviceToDevice, stream);
  hipMemcpyAsync(bias_qkv + 1536, bv, 768*4, hipMemcpyDeviceToDevice, stream);
  cvt16<<<3072, blk, 0, stream>>>(x, xbf);
  // fused QKV
  gemm_bt<64,128,0,1><<<dim3(18,128), blk, 0, stream>>>(xbf, WqkvT, bias_qkv, nullptr, qkv, 8192, 2304, 768);
  vtrans<<<dim3(16,96), blk, 0, stream>>>(qkv + 1536, vtb, 2304);
  attn_fwd<<<dim3(16,96), blk, 0, stream>>>(qkv, qkv + 768, vtb, ctx, 2304);
  gemm_bt<64,128,0,2><<<dim3(6,128), blk, 0, stream>>>(ctx, WoT, bo, attn_dense, attn_dense_bf, 8192, 768, 768);
  // adapter 1
  gemm_bt<64,64,1,0><<<dim3(1,128), blk, 0, stream>>>(attn_dense_bf, A1dwT, a1_db, dbuf, nullptr, 8192, 64, 768);
  hipMemsetAsync(ws + oEsum, 0, zeroBytes, stream);
  adp_gather<<<8192, blk, 0, stream>>>(dbuf, node_idx, edge_idx, esum, ecnt);
  adp_edge<<<1024, blk, 0, stream>>>(esum, ecnt, edge_types, a1_temb, ebuf);
  adp_scatter<<<8192, blk, 0, stream>>>(ebuf, node_idx, edge_idx, nsum, ncnt);
  adp_node<<<2048, blk, 0, stream>>>(nsum, ncnt, ubuf);
  gemm_bt<64,128,0,0><<<dim3(6,128), blk, 0, stream>>>(ubuf, A1uwT, a1_ub, adb, nullptr, 8192, 768, 64);
  ln3<<<8192, blk, 0, stream>>>(attn_dense, adb, x, ln1_g, ln1_b, attn_out, attn_out_bf);
  // FFN
  gemm_bt<64,128,1,1><<<dim3(24,128), blk, 0, stream>>>(attn_out_bf, WiT, bi, nullptr, inter, 8192, 3072, 768);
  gemm_bt<64,128,0,2><<<dim3(6,128), blk, 0, stream>>>(inter, Wd2T, bd2, ffb, ffb_bf, 8192, 768, 3072);
  // adapter 2
  gemm_bt<64,64,1,0><<<dim3(1,128), blk, 0, stream>>>(ffb_bf, A2dwT, a2_db, dbuf, nullptr, 8192, 64, 768);
  hipMemsetAsync(ws + oEsum, 0, zeroBytes, stream);
  adp_gather<<<8192, blk, 0, stream>>>(dbuf, node_idx, edge_idx, esum, ecnt);
  adp_edge<<<1024, blk, 0, stream>>>(esum, ecnt, edge_types, a2_temb, ebuf);
  adp_scatter<<<8192, blk, 0, stream>>>(ebuf, node_idx, edge_idx, nsum, ncnt);
  adp_node<<<2048, blk, 0, stream>>>(nsum, ncnt, ubuf);
  gemm_bt<64,128,0,0><<<dim3(6,128), blk, 0, stream>>>(ubuf, A2uwT, a2_ub, adb, nullptr, 8192, 768, 64);
  ln3<<<8192, blk, 0, stream>>>(ffb, adb, attn_out, ln2_g, ln2_b, (float*)d_out, nullptr);
}